// Round 5
// baseline (181.415 us; speedup 1.0000x reference)
//
#include <hip/hip_runtime.h>
#include <hip/hip_bf16.h>

#define NN 50000
#define NE 800000
#define HD 128
#define RB 64                   // rows per GEMM block (4 per thread)

#define BINSH 9                 // 512 nodes per coarse bin
#define NBINS 98                // ceil(50000/512)
#define BINCAP 9216             // slop capacity (mean 8163, 11.6 sigma)
#define CHUNK 4096              // edges per binplace block
#define MAXBIN 9216

// f32 -> bf16 round-to-nearest-even
__device__ inline unsigned short f2bf(float f) {
    union { float f; unsigned u; } c; c.f = f;
    unsigned r = c.u + 0x7fff + ((c.u >> 16) & 1);
    return (unsigned short)(r >> 16);
}

// load 4 bf16 (8B) -> float4
__device__ inline float4 ld_bf4(const unsigned short* p) {
    uint2 q = *(const uint2*)p;
    float4 r;
    r.x = __uint_as_float(q.x << 16);
    r.y = __uint_as_float(q.x & 0xffff0000u);
    r.z = __uint_as_float(q.y << 16);
    r.w = __uint_as_float(q.y & 0xffff0000u);
    return r;
}

// ---------------- init bin cursors ----------------
__global__ void k_init(int* cursor) {
    int t = threadIdx.x;
    if (t < NBINS) cursor[t] = t * BINCAP;
}

// ---------------- pass 1: bin edges by dst>>9, coalesced writes ----------------
__global__ __launch_bounds__(256) void k_binplace(
        const int* __restrict__ ei, int* cursor, unsigned* __restrict__ binned) {
    __shared__ unsigned stage[CHUNK];
    __shared__ unsigned char sbin[CHUNK];
    __shared__ int hist[NBINS], base[NBINS], cur[NBINS], gbase[NBINS];
    int t = threadIdx.x;
    int e0 = blockIdx.x * CHUNK;
    int nE = NE - e0; if (nE > CHUNK) nE = CHUNK;

    if (t < NBINS) hist[t] = 0;
    __syncthreads();

    unsigned keys[16], packs[16];
    #pragma unroll
    for (int i = 0; i < 16; ++i) {
        int li = i * 256 + t;
        keys[i] = 0xffffffffu;
        if (li < nE) {
            int e = e0 + li;
            unsigned s = (unsigned)ei[e];
            unsigned d = (unsigned)ei[NE + e];
            if (s < NN && d < NN) {
                keys[i] = d >> BINSH;
                packs[i] = (s << BINSH) | (d & ((1u << BINSH) - 1));
                atomicAdd(&hist[keys[i]], 1);
            }
        }
    }
    __syncthreads();
    if (t == 0) { int a = 0; for (int b = 0; b < NBINS; ++b) { base[b] = a; a += hist[b]; } }
    __syncthreads();
    if (t < NBINS) {
        cur[t] = base[t];
        if (hist[t] > 0) gbase[t] = atomicAdd(&cursor[t], hist[t]);
    }
    __syncthreads();
    #pragma unroll
    for (int i = 0; i < 16; ++i) {
        if (keys[i] != 0xffffffffu) {
            int p = atomicAdd(&cur[keys[i]], 1);
            stage[p] = packs[i];
            sbin[p] = (unsigned char)keys[i];
        }
    }
    __syncthreads();
    int tot = cur[NBINS - 1];   // == number of valid edges staged
    for (int j = t; j < tot; j += 256) {
        unsigned b = sbin[j];
        binned[gbase[b] + (j - base[b])] = stage[j];
    }
}

// ---------------- pass 2: per-bin sort -> CSR (u16 src), deg/dinv/rowstart ----------------
__global__ __launch_bounds__(256) void k_csr(
        const unsigned* __restrict__ binned, const int* __restrict__ cursor,
        unsigned short* __restrict__ csr, int* __restrict__ rowstart,
        int* __restrict__ degi, float* __restrict__ dinv) {
    __shared__ unsigned ent[MAXBIN];
    __shared__ unsigned short outv[MAXBIN];
    __shared__ int hist[512], rs[512], cur[512];
    __shared__ int sizes[NBINS];
    int t = threadIdx.x, b = blockIdx.x;

    if (t < NBINS) sizes[t] = cursor[t] - t * BINCAP;
    __syncthreads();
    int bsize = sizes[b]; if (bsize > MAXBIN) bsize = MAXBIN;
    int bstart = 0;
    for (int i = 0; i < b; ++i) bstart += sizes[i];

    for (int j = t; j < bsize; j += 256) ent[j] = binned[b * BINCAP + j];
    for (int k = t; k < 512; k += 256) hist[k] = 0;
    __syncthreads();
    for (int j = t; j < bsize; j += 256) atomicAdd(&hist[ent[j] & 511], 1);
    __syncthreads();
    if (t == 0) { int a = 0; for (int k = 0; k < 512; ++k) { rs[k] = a; a += hist[k]; } }
    __syncthreads();
    for (int k = t; k < 512; k += 256) {
        cur[k] = rs[k];
        int g = (b << BINSH) + k;
        if (g < NN) {
            rowstart[g] = bstart + rs[k];
            degi[g] = hist[k];
            dinv[g] = rsqrtf((float)(hist[k] + 1));
        }
    }
    __syncthreads();
    for (int j = t; j < bsize; j += 256) {
        unsigned v = ent[j];
        int p = atomicAdd(&cur[v & 511], 1);
        outv[p] = (unsigned short)(v >> BINSH);
    }
    __syncthreads();
    for (int j = t; j < bsize; j += 256) csr[bstart + j] = outv[j];
}

// ---------------- GEMM: ybf = bf16((x @ W) * dinv[n]), 4x8 register tile ----------------
__global__ __launch_bounds__(256) void k_gemm_xw(
        const float* __restrict__ x, const float* __restrict__ W,
        const float* __restrict__ dinv, unsigned short* __restrict__ ybf) {
    __shared__ float Ws[HD * HD];        // 64 KB
    __shared__ float xs[RB][HD + 1];     // 33 KB
    int t = threadIdx.x;
    int rowBase = blockIdx.x * RB;

    const float4* W4 = (const float4*)W;
    float4* Ws4 = (float4*)Ws;
    #pragma unroll
    for (int i = 0; i < (HD * HD / 4) / 256; ++i)
        Ws4[t + i * 256] = W4[t + i * 256];

    #pragma unroll
    for (int i = 0; i < RB * (HD / 4) / 256; ++i) {
        int f = t + i * 256;
        int r = f >> 5, c = (f & 31) * 4;
        int gr = rowBase + r;
        float4 v = make_float4(0.f, 0.f, 0.f, 0.f);
        if (gr < NN) v = *(const float4*)&x[(size_t)gr * HD + c];
        *(float4*)&xs[r][c] = v;
    }
    __syncthreads();

    int rg = t >> 4;           // 0..15 -> rows rg*4 .. rg*4+3
    int cg = t & 15;
    int c0 = cg * 4;
    float acc[4][8];
    #pragma unroll
    for (int j = 0; j < 4; ++j)
        #pragma unroll
        for (int k = 0; k < 8; ++k) acc[j][k] = 0.f;

    #pragma unroll 2
    for (int h = 0; h < HD; ++h) {
        float4 w0 = *(const float4*)&Ws[h * HD + c0];
        float4 w1 = *(const float4*)&Ws[h * HD + c0 + 64];
        #pragma unroll
        for (int j = 0; j < 4; ++j) {
            float xv = xs[rg * 4 + j][h];
            acc[j][0] += xv * w0.x; acc[j][1] += xv * w0.y;
            acc[j][2] += xv * w0.z; acc[j][3] += xv * w0.w;
            acc[j][4] += xv * w1.x; acc[j][5] += xv * w1.y;
            acc[j][6] += xv * w1.z; acc[j][7] += xv * w1.w;
        }
    }

    #pragma unroll
    for (int j = 0; j < 4; ++j) {
        int gr = rowBase + rg * 4 + j;
        if (gr >= NN) continue;
        float dv = dinv[gr];
        ushort4 p0, p1;
        p0.x = f2bf(acc[j][0] * dv); p0.y = f2bf(acc[j][1] * dv);
        p0.z = f2bf(acc[j][2] * dv); p0.w = f2bf(acc[j][3] * dv);
        p1.x = f2bf(acc[j][4] * dv); p1.y = f2bf(acc[j][5] * dv);
        p1.z = f2bf(acc[j][6] * dv); p1.w = f2bf(acc[j][7] * dv);
        size_t basei = (size_t)gr * HD;
        *(ushort4*)&ybf[basei + c0]      = p0;
        *(ushort4*)&ybf[basei + c0 + 64] = p1;
    }
}

// ---------------- gather: z[n] = dinv[n]*(y[n] + sum y[src]) + b ----------------
__global__ __launch_bounds__(256) void k_gather(
        const unsigned short* __restrict__ csr, const int* __restrict__ rowstart,
        const int* __restrict__ degi, const float* __restrict__ dinv,
        const unsigned short* __restrict__ ybf, const float* __restrict__ b,
        float* __restrict__ z) {
    int t = threadIdx.x;
    int n = blockIdx.x * 8 + (t >> 5);
    int lane = t & 31;
    if (n >= NN) return;
    int c = lane * 4;

    float4 acc = ld_bf4(&ybf[(size_t)n * HD + c]);   // self-loop term
    int beg = rowstart[n];
    int dg = degi[n];

    int i = 0;
    for (; i + 4 <= dg; i += 4) {
        int s0 = csr[beg + i + 0];
        int s1 = csr[beg + i + 1];
        int s2 = csr[beg + i + 2];
        int s3 = csr[beg + i + 3];
        float4 v0 = ld_bf4(&ybf[(size_t)s0 * HD + c]);
        float4 v1 = ld_bf4(&ybf[(size_t)s1 * HD + c]);
        float4 v2 = ld_bf4(&ybf[(size_t)s2 * HD + c]);
        float4 v3 = ld_bf4(&ybf[(size_t)s3 * HD + c]);
        acc.x += v0.x + v1.x + v2.x + v3.x;
        acc.y += v0.y + v1.y + v2.y + v3.y;
        acc.z += v0.z + v1.z + v2.z + v3.z;
        acc.w += v0.w + v1.w + v2.w + v3.w;
    }
    for (; i < dg; ++i) {
        int s = csr[beg + i];
        float4 v = ld_bf4(&ybf[(size_t)s * HD + c]);
        acc.x += v.x; acc.y += v.y; acc.z += v.z; acc.w += v.w;
    }

    float dv = dinv[n];
    float4 bv = *(const float4*)&b[c];
    acc.x = acc.x * dv + bv.x;
    acc.y = acc.y * dv + bv.y;
    acc.z = acc.z * dv + bv.z;
    acc.w = acc.w * dv + bv.w;
    *(float4*)&z[(size_t)n * HD + c] = acc;
}

// ---------------- bilinear: t = z@Wb (4x8 reg tile); pos=<t,z>, neg=<t,z[perm]> ----------------
__global__ __launch_bounds__(256) void k_bilinear(
        const float* __restrict__ z, const float* __restrict__ Wb,
        const float* __restrict__ bb, const int* __restrict__ perm,
        float* __restrict__ out) {
    __shared__ float Ws[HD * HD];        // 64 KB
    __shared__ float zs[RB][HD + 1];     // 33 KB
    int t = threadIdx.x;
    int rowBase = blockIdx.x * RB;

    const float4* W4 = (const float4*)Wb;
    float4* Ws4 = (float4*)Ws;
    #pragma unroll
    for (int i = 0; i < (HD * HD / 4) / 256; ++i)
        Ws4[t + i * 256] = W4[t + i * 256];

    #pragma unroll
    for (int i = 0; i < RB * (HD / 4) / 256; ++i) {
        int f = t + i * 256;
        int r = f >> 5, c = (f & 31) * 4;
        int gr = rowBase + r;
        float4 v = make_float4(0.f, 0.f, 0.f, 0.f);
        if (gr < NN) v = *(const float4*)&z[(size_t)gr * HD + c];
        *(float4*)&zs[r][c] = v;
    }
    __syncthreads();

    int rg = t >> 4;
    int cg = t & 15;
    int c0 = cg * 4;
    float acc[4][8];
    #pragma unroll
    for (int j = 0; j < 4; ++j)
        #pragma unroll
        for (int k = 0; k < 8; ++k) acc[j][k] = 0.f;

    #pragma unroll 2
    for (int h = 0; h < HD; ++h) {
        float4 w0 = *(const float4*)&Ws[h * HD + c0];
        float4 w1 = *(const float4*)&Ws[h * HD + c0 + 64];
        #pragma unroll
        for (int j = 0; j < 4; ++j) {
            float zv = zs[rg * 4 + j][h];
            acc[j][0] += zv * w0.x; acc[j][1] += zv * w0.y;
            acc[j][2] += zv * w0.z; acc[j][3] += zv * w0.w;
            acc[j][4] += zv * w1.x; acc[j][5] += zv * w1.y;
            acc[j][6] += zv * w1.z; acc[j][7] += zv * w1.w;
        }
    }

    float bbv = bb[0];
    #pragma unroll
    for (int j = 0; j < 4; ++j) {
        int lr = rg * 4 + j;
        int gr = rowBase + lr;
        float pos = 0.f, neg = 0.f;
        #pragma unroll
        for (int k = 0; k < 4; ++k) {
            pos += acc[j][k]     * zs[lr][c0 + k];
            pos += acc[j][4 + k] * zs[lr][c0 + 64 + k];
        }
        if (gr < NN) {
            unsigned p = (unsigned)perm[gr];
            float4 zp0 = *(const float4*)&z[(size_t)p * HD + c0];
            float4 zp1 = *(const float4*)&z[(size_t)p * HD + c0 + 64];
            neg = acc[j][0] * zp0.x + acc[j][1] * zp0.y
                + acc[j][2] * zp0.z + acc[j][3] * zp0.w
                + acc[j][4] * zp1.x + acc[j][5] * zp1.y
                + acc[j][6] * zp1.z + acc[j][7] * zp1.w;
        }
        #pragma unroll
        for (int off = 8; off; off >>= 1) {
            pos += __shfl_xor(pos, off);
            neg += __shfl_xor(neg, off);
        }
        if (cg == 0 && gr < NN) {
            out[gr] = pos + bbv;
            out[NN + gr] = neg + bbv;
        }
    }
}

extern "C" void kernel_launch(void* const* d_in, const int* in_sizes, int n_in,
                              void* d_out, int out_size, void* d_ws, size_t ws_size,
                              hipStream_t stream) {
    const float* x    = (const float*)d_in[0];
    const float* W    = (const float*)d_in[1];
    const float* b    = (const float*)d_in[2];
    const float* Wb   = (const float*)d_in[3];
    const float* bb   = (const float*)d_in[4];
    const int*   ei   = (const int*)d_in[5];
    const int*   perm = (const int*)d_in[6];
    float* out = (float*)d_out;

    char* ws = (char*)d_ws;
    int*            cursor   = (int*)(ws + 0);               // 4 KB
    float*          dinv     = (float*)(ws + 0x1000);        // 200 KB
    int*            rowstart = (int*)(ws + 0x33000);         // 200 KB
    int*            degi     = (int*)(ws + 0x65000);         // 200 KB
    unsigned short* csr      = (unsigned short*)(ws + 0x97000);   // 1.6 MB
    unsigned*       binned   = (unsigned*)(ws + 0x240000);   // 3.6 MB
    unsigned short* ybf      = (unsigned short*)(ws + 0x600000);  // 12.8 MB
    float*          z        = (float*)(ws + 0x2000000);     // 25.6 MB

    k_init<<<1, 128, 0, stream>>>(cursor);
    k_binplace<<<(NE + CHUNK - 1) / CHUNK, 256, 0, stream>>>(ei, cursor, binned);
    k_csr<<<NBINS, 256, 0, stream>>>(binned, cursor, csr, rowstart, degi, dinv);
    k_gemm_xw<<<(NN + RB - 1) / RB, 256, 0, stream>>>(x, W, dinv, ybf);
    k_gather<<<(NN + 7) / 8, 256, 0, stream>>>(csr, rowstart, degi, dinv, ybf, b, z);
    k_bilinear<<<(NN + RB - 1) / RB, 256, 0, stream>>>(z, Wb, bb, perm, out);
}

// Round 6
// 152.063 us; speedup vs baseline: 1.1930x; 1.1930x over previous
//
#include <hip/hip_runtime.h>
#include <hip/hip_bf16.h>

#define NN 50000
#define NE 800000
#define HD 128
#define RB 64                   // rows per GEMM block (4 per thread)

#define BINSH 9                 // 512 nodes per coarse bin
#define NBINS 98                // ceil(50000/512)
#define BINCAP 9216             // slop capacity (mean 8163, 11.6 sigma)
#define CHUNK 1024              // edges per binplace block (782 blocks)
#define MAXBIN 9216

// f32 -> bf16 round-to-nearest-even
__device__ inline unsigned short f2bf(float f) {
    union { float f; unsigned u; } c; c.f = f;
    unsigned r = c.u + 0x7fff + ((c.u >> 16) & 1);
    return (unsigned short)(r >> 16);
}

__device__ inline float bflo(unsigned u) { return __uint_as_float(u << 16); }
__device__ inline float bfhi(unsigned u) { return __uint_as_float(u & 0xffff0000u); }

// load 4 bf16 (8B) -> float4
__device__ inline float4 ld_bf4(const unsigned short* p) {
    uint2 q = *(const uint2*)p;
    float4 r;
    r.x = bflo(q.x); r.y = bfhi(q.x);
    r.z = bflo(q.y); r.w = bfhi(q.y);
    return r;
}

// ---------------- init bin cursors ----------------
__global__ void k_init(int* cursor) {
    int t = threadIdx.x;
    if (t < NBINS) cursor[t] = t * BINCAP;
}

// ---------------- pass 1: bin edges by dst>>9, coalesced writes ----------------
__global__ __launch_bounds__(256) void k_binplace(
        const int* __restrict__ ei, int* cursor, unsigned* __restrict__ binned) {
    __shared__ unsigned stage[CHUNK];
    __shared__ unsigned char sbin[CHUNK];
    __shared__ int hist[NBINS], base[NBINS], cur[NBINS], gbase[NBINS];
    int t = threadIdx.x;
    int e0 = blockIdx.x * CHUNK;
    int nE = NE - e0; if (nE > CHUNK) nE = CHUNK;

    if (t < NBINS) hist[t] = 0;
    __syncthreads();

    unsigned keys[CHUNK / 256], packs[CHUNK / 256];
    #pragma unroll
    for (int i = 0; i < CHUNK / 256; ++i) {
        int li = i * 256 + t;
        keys[i] = 0xffffffffu;
        if (li < nE) {
            int e = e0 + li;
            unsigned s = (unsigned)ei[e];
            unsigned d = (unsigned)ei[NE + e];
            if (s < NN && d < NN) {
                keys[i] = d >> BINSH;
                packs[i] = (s << BINSH) | (d & ((1u << BINSH) - 1));
                atomicAdd(&hist[keys[i]], 1);
            }
        }
    }
    __syncthreads();
    if (t == 0) { int a = 0; for (int b = 0; b < NBINS; ++b) { base[b] = a; a += hist[b]; } }
    __syncthreads();
    if (t < NBINS) {
        cur[t] = base[t];
        if (hist[t] > 0) gbase[t] = atomicAdd(&cursor[t], hist[t]);
    }
    __syncthreads();
    #pragma unroll
    for (int i = 0; i < CHUNK / 256; ++i) {
        if (keys[i] != 0xffffffffu) {
            int p = atomicAdd(&cur[keys[i]], 1);
            stage[p] = packs[i];
            sbin[p] = (unsigned char)keys[i];
        }
    }
    __syncthreads();
    int tot = cur[NBINS - 1];   // == number of valid edges staged
    for (int j = t; j < tot; j += 256) {
        unsigned b = sbin[j];
        binned[gbase[b] + (j - base[b])] = stage[j];
    }
}

// ---------------- pass 2: per-bin sort -> CSR (u16 src), deg/dinv/rowstart ----------------
__global__ __launch_bounds__(256) void k_csr(
        const unsigned* __restrict__ binned, const int* __restrict__ cursor,
        unsigned short* __restrict__ csr, int* __restrict__ rowstart,
        int* __restrict__ degi, float* __restrict__ dinv) {
    __shared__ unsigned ent[MAXBIN];
    __shared__ unsigned short outv[MAXBIN];
    __shared__ int hist[512], rs[512], cur[512];
    __shared__ int sizes[NBINS];
    int t = threadIdx.x, b = blockIdx.x;

    if (t < NBINS) sizes[t] = cursor[t] - t * BINCAP;
    __syncthreads();
    int bsize = sizes[b]; if (bsize > MAXBIN) bsize = MAXBIN;
    int bstart = 0;
    for (int i = 0; i < b; ++i) bstart += sizes[i];

    for (int j = t; j < bsize; j += 256) ent[j] = binned[b * BINCAP + j];
    for (int k = t; k < 512; k += 256) hist[k] = 0;
    __syncthreads();
    for (int j = t; j < bsize; j += 256) atomicAdd(&hist[ent[j] & 511], 1);
    __syncthreads();
    if (t == 0) { int a = 0; for (int k = 0; k < 512; ++k) { rs[k] = a; a += hist[k]; } }
    __syncthreads();
    for (int k = t; k < 512; k += 256) {
        cur[k] = rs[k];
        int g = (b << BINSH) + k;
        if (g < NN) {
            rowstart[g] = bstart + rs[k];
            degi[g] = hist[k];
            dinv[g] = rsqrtf((float)(hist[k] + 1));
        }
    }
    __syncthreads();
    for (int j = t; j < bsize; j += 256) {
        unsigned v = ent[j];
        int p = atomicAdd(&cur[v & 511], 1);
        outv[p] = (unsigned short)(v >> BINSH);
    }
    __syncthreads();
    for (int j = t; j < bsize; j += 256) csr[bstart + j] = outv[j];
}

// ---------------- GEMM: ybf = bf16((x @ W) * dinv[n]), 4x8 reg tile, bf16 W in LDS ----------------
__global__ __launch_bounds__(256, 2) void k_gemm_xw(
        const float* __restrict__ x, const float* __restrict__ W,
        const float* __restrict__ dinv, unsigned short* __restrict__ ybf) {
    __shared__ unsigned short Wsb[HD * HD];   // 32 KB (bf16)
    __shared__ float xs[RB][HD + 1];          // 33 KB
    int t = threadIdx.x;
    int rowBase = blockIdx.x * RB;

    const float4* W4 = (const float4*)W;
    #pragma unroll
    for (int i = 0; i < (HD * HD / 4) / 256; ++i) {   // 16 iters
        int f = t + i * 256;
        float4 v = W4[f];
        ushort4 p;
        p.x = f2bf(v.x); p.y = f2bf(v.y); p.z = f2bf(v.z); p.w = f2bf(v.w);
        *(ushort4*)&Wsb[f * 4] = p;
    }

    #pragma unroll
    for (int i = 0; i < RB * (HD / 4) / 256; ++i) {
        int f = t + i * 256;
        int r = f >> 5, c = (f & 31) * 4;
        int gr = rowBase + r;
        float4 v = make_float4(0.f, 0.f, 0.f, 0.f);
        if (gr < NN) v = *(const float4*)&x[(size_t)gr * HD + c];
        *(float4*)&xs[r][c] = v;
    }
    __syncthreads();

    int rg = t >> 4;           // 0..15 -> rows rg*4 .. rg*4+3
    int cg = t & 15;
    int c0 = cg * 4;
    float acc[4][8];
    #pragma unroll
    for (int j = 0; j < 4; ++j)
        #pragma unroll
        for (int k = 0; k < 8; ++k) acc[j][k] = 0.f;

    #pragma unroll 4
    for (int h = 0; h < HD; ++h) {
        uint2 u0 = *(const uint2*)&Wsb[h * HD + c0];
        uint2 u1 = *(const uint2*)&Wsb[h * HD + c0 + 64];
        float w0 = bflo(u0.x), w1 = bfhi(u0.x), w2 = bflo(u0.y), w3 = bfhi(u0.y);
        float w4 = bflo(u1.x), w5 = bfhi(u1.x), w6 = bflo(u1.y), w7 = bfhi(u1.y);
        #pragma unroll
        for (int j = 0; j < 4; ++j) {
            float xv = xs[rg * 4 + j][h];
            acc[j][0] += xv * w0; acc[j][1] += xv * w1;
            acc[j][2] += xv * w2; acc[j][3] += xv * w3;
            acc[j][4] += xv * w4; acc[j][5] += xv * w5;
            acc[j][6] += xv * w6; acc[j][7] += xv * w7;
        }
    }

    #pragma unroll
    for (int j = 0; j < 4; ++j) {
        int gr = rowBase + rg * 4 + j;
        if (gr >= NN) continue;
        float dv = dinv[gr];
        ushort4 p0, p1;
        p0.x = f2bf(acc[j][0] * dv); p0.y = f2bf(acc[j][1] * dv);
        p0.z = f2bf(acc[j][2] * dv); p0.w = f2bf(acc[j][3] * dv);
        p1.x = f2bf(acc[j][4] * dv); p1.y = f2bf(acc[j][5] * dv);
        p1.z = f2bf(acc[j][6] * dv); p1.w = f2bf(acc[j][7] * dv);
        size_t basei = (size_t)gr * HD;
        *(ushort4*)&ybf[basei + c0]      = p0;
        *(ushort4*)&ybf[basei + c0 + 64] = p1;
    }
}

// ---------------- gather: z[n] = dinv[n]*(y[n] + sum y[src]) + b ----------------
__global__ __launch_bounds__(256) void k_gather(
        const unsigned short* __restrict__ csr, const int* __restrict__ rowstart,
        const int* __restrict__ degi, const float* __restrict__ dinv,
        const unsigned short* __restrict__ ybf, const float* __restrict__ b,
        float* __restrict__ z) {
    int t = threadIdx.x;
    int n = blockIdx.x * 8 + (t >> 5);
    int lane = t & 31;
    if (n >= NN) return;
    int c = lane * 4;

    float4 acc = ld_bf4(&ybf[(size_t)n * HD + c]);   // self-loop term
    int beg = rowstart[n];
    int dg = degi[n];

    int i = 0;
    for (; i + 4 <= dg; i += 4) {
        int s0 = csr[beg + i + 0];
        int s1 = csr[beg + i + 1];
        int s2 = csr[beg + i + 2];
        int s3 = csr[beg + i + 3];
        float4 v0 = ld_bf4(&ybf[(size_t)s0 * HD + c]);
        float4 v1 = ld_bf4(&ybf[(size_t)s1 * HD + c]);
        float4 v2 = ld_bf4(&ybf[(size_t)s2 * HD + c]);
        float4 v3 = ld_bf4(&ybf[(size_t)s3 * HD + c]);
        acc.x += v0.x + v1.x + v2.x + v3.x;
        acc.y += v0.y + v1.y + v2.y + v3.y;
        acc.z += v0.z + v1.z + v2.z + v3.z;
        acc.w += v0.w + v1.w + v2.w + v3.w;
    }
    for (; i < dg; ++i) {
        int s = csr[beg + i];
        float4 v = ld_bf4(&ybf[(size_t)s * HD + c]);
        acc.x += v.x; acc.y += v.y; acc.z += v.z; acc.w += v.w;
    }

    float dv = dinv[n];
    float4 bv = *(const float4*)&b[c];
    acc.x = acc.x * dv + bv.x;
    acc.y = acc.y * dv + bv.y;
    acc.z = acc.z * dv + bv.z;
    acc.w = acc.w * dv + bv.w;
    *(float4*)&z[(size_t)n * HD + c] = acc;
}

// ---------------- bilinear: t = z@Wb (4x8 reg tile, bf16 Wb); pos=<t,z>, neg=<t,z[perm]> ----------------
__global__ __launch_bounds__(256, 2) void k_bilinear(
        const float* __restrict__ z, const float* __restrict__ Wb,
        const float* __restrict__ bb, const int* __restrict__ perm,
        float* __restrict__ out) {
    __shared__ unsigned short Wsb[HD * HD];   // 32 KB (bf16)
    __shared__ float zs[RB][HD + 1];          // 33 KB
    int t = threadIdx.x;
    int rowBase = blockIdx.x * RB;

    const float4* W4 = (const float4*)Wb;
    #pragma unroll
    for (int i = 0; i < (HD * HD / 4) / 256; ++i) {
        int f = t + i * 256;
        float4 v = W4[f];
        ushort4 p;
        p.x = f2bf(v.x); p.y = f2bf(v.y); p.z = f2bf(v.z); p.w = f2bf(v.w);
        *(ushort4*)&Wsb[f * 4] = p;
    }

    #pragma unroll
    for (int i = 0; i < RB * (HD / 4) / 256; ++i) {
        int f = t + i * 256;
        int r = f >> 5, c = (f & 31) * 4;
        int gr = rowBase + r;
        float4 v = make_float4(0.f, 0.f, 0.f, 0.f);
        if (gr < NN) v = *(const float4*)&z[(size_t)gr * HD + c];
        *(float4*)&zs[r][c] = v;
    }
    __syncthreads();

    int rg = t >> 4;
    int cg = t & 15;
    int c0 = cg * 4;
    float acc[4][8];
    #pragma unroll
    for (int j = 0; j < 4; ++j)
        #pragma unroll
        for (int k = 0; k < 8; ++k) acc[j][k] = 0.f;

    #pragma unroll 4
    for (int h = 0; h < HD; ++h) {
        uint2 u0 = *(const uint2*)&Wsb[h * HD + c0];
        uint2 u1 = *(const uint2*)&Wsb[h * HD + c0 + 64];
        float w0 = bflo(u0.x), w1 = bfhi(u0.x), w2 = bflo(u0.y), w3 = bfhi(u0.y);
        float w4 = bflo(u1.x), w5 = bfhi(u1.x), w6 = bflo(u1.y), w7 = bfhi(u1.y);
        #pragma unroll
        for (int j = 0; j < 4; ++j) {
            float zv = zs[rg * 4 + j][h];
            acc[j][0] += zv * w0; acc[j][1] += zv * w1;
            acc[j][2] += zv * w2; acc[j][3] += zv * w3;
            acc[j][4] += zv * w4; acc[j][5] += zv * w5;
            acc[j][6] += zv * w6; acc[j][7] += zv * w7;
        }
    }

    float bbv = bb[0];
    #pragma unroll
    for (int j = 0; j < 4; ++j) {
        int lr = rg * 4 + j;
        int gr = rowBase + lr;
        float pos = 0.f, neg = 0.f;
        #pragma unroll
        for (int k = 0; k < 4; ++k) {
            pos += acc[j][k]     * zs[lr][c0 + k];
            pos += acc[j][4 + k] * zs[lr][c0 + 64 + k];
        }
        if (gr < NN) {
            unsigned p = (unsigned)perm[gr];
            float4 zp0 = *(const float4*)&z[(size_t)p * HD + c0];
            float4 zp1 = *(const float4*)&z[(size_t)p * HD + c0 + 64];
            neg = acc[j][0] * zp0.x + acc[j][1] * zp0.y
                + acc[j][2] * zp0.z + acc[j][3] * zp0.w
                + acc[j][4] * zp1.x + acc[j][5] * zp1.y
                + acc[j][6] * zp1.z + acc[j][7] * zp1.w;
        }
        #pragma unroll
        for (int off = 8; off; off >>= 1) {
            pos += __shfl_xor(pos, off);
            neg += __shfl_xor(neg, off);
        }
        if (cg == 0 && gr < NN) {
            out[gr] = pos + bbv;
            out[NN + gr] = neg + bbv;
        }
    }
}

extern "C" void kernel_launch(void* const* d_in, const int* in_sizes, int n_in,
                              void* d_out, int out_size, void* d_ws, size_t ws_size,
                              hipStream_t stream) {
    const float* x    = (const float*)d_in[0];
    const float* W    = (const float*)d_in[1];
    const float* b    = (const float*)d_in[2];
    const float* Wb   = (const float*)d_in[3];
    const float* bb   = (const float*)d_in[4];
    const int*   ei   = (const int*)d_in[5];
    const int*   perm = (const int*)d_in[6];
    float* out = (float*)d_out;

    char* ws = (char*)d_ws;
    int*            cursor   = (int*)(ws + 0);               // 4 KB
    float*          dinv     = (float*)(ws + 0x1000);        // 200 KB
    int*            rowstart = (int*)(ws + 0x33000);         // 200 KB
    int*            degi     = (int*)(ws + 0x65000);         // 200 KB
    unsigned short* csr      = (unsigned short*)(ws + 0x97000);   // 1.6 MB
    unsigned*       binned   = (unsigned*)(ws + 0x240000);   // 3.6 MB
    unsigned short* ybf      = (unsigned short*)(ws + 0x600000);  // 12.8 MB
    float*          z        = (float*)(ws + 0x2000000);     // 25.6 MB

    k_init<<<1, 128, 0, stream>>>(cursor);
    k_binplace<<<(NE + CHUNK - 1) / CHUNK, 256, 0, stream>>>(ei, cursor, binned);
    k_csr<<<NBINS, 256, 0, stream>>>(binned, cursor, csr, rowstart, degi, dinv);
    k_gemm_xw<<<(NN + RB - 1) / RB, 256, 0, stream>>>(x, W, dinv, ybf);
    k_gather<<<(NN + 7) / 8, 256, 0, stream>>>(csr, rowstart, degi, dinv, ybf, b, z);
    k_bilinear<<<(NN + RB - 1) / RB, 256, 0, stream>>>(z, Wb, bb, perm, out);
}

// Round 7
// 135.139 us; speedup vs baseline: 1.3424x; 1.1252x over previous
//
#include <hip/hip_runtime.h>
#include <hip/hip_bf16.h>

#define NN 50000
#define NE 800000
#define HD 128
#define WPAD 136                // transposed-W LDS row stride (shorts), 16B-aligned

#define BINSH 9                 // 512 nodes per coarse bin
#define NBINS 98                // ceil(50000/512)
#define BINCAP 9216             // slop capacity (mean 8163, 11.6 sigma)
#define CHUNK 1024              // edges per binplace block (782 blocks)
#define MAXBIN 9216

typedef __attribute__((ext_vector_type(8))) short bf16x8;
typedef __attribute__((ext_vector_type(4))) float f32x4;

// f32 -> bf16 round-to-nearest-even
__device__ inline unsigned short f2bf(float f) {
    union { float f; unsigned u; } c; c.f = f;
    unsigned r = c.u + 0x7fff + ((c.u >> 16) & 1);
    return (unsigned short)(r >> 16);
}

__device__ inline float bflo(unsigned u) { return __uint_as_float(u << 16); }
__device__ inline float bfhi(unsigned u) { return __uint_as_float(u & 0xffff0000u); }

// split f32 into hi bf16 + lo bf16 (residual)
__device__ inline void split2(float v, unsigned short* h, unsigned short* l) {
    unsigned short hh = f2bf(v);
    float fh = __uint_as_float(((unsigned)hh) << 16);
    *h = hh;
    *l = f2bf(v - fh);
}

// load 4 bf16 (8B) -> float4
__device__ inline float4 ld_bf4(const unsigned short* p) {
    uint2 q = *(const uint2*)p;
    float4 r;
    r.x = bflo(q.x); r.y = bfhi(q.x);
    r.z = bflo(q.y); r.w = bfhi(q.y);
    return r;
}

// ---------------- init bin cursors ----------------
__global__ void k_init(int* cursor) {
    int t = threadIdx.x;
    if (t < NBINS) cursor[t] = t * BINCAP;
}

// ---------------- pass 1: bin edges by dst>>9, coalesced writes ----------------
__global__ __launch_bounds__(256) void k_binplace(
        const int* __restrict__ ei, int* cursor, unsigned* __restrict__ binned) {
    __shared__ unsigned stage[CHUNK];
    __shared__ unsigned char sbin[CHUNK];
    __shared__ int hist[NBINS], base[NBINS], cur[NBINS], gbase[NBINS];
    int t = threadIdx.x;
    int e0 = blockIdx.x * CHUNK;
    int nE = NE - e0; if (nE > CHUNK) nE = CHUNK;

    if (t < NBINS) hist[t] = 0;
    __syncthreads();

    unsigned keys[CHUNK / 256], packs[CHUNK / 256];
    #pragma unroll
    for (int i = 0; i < CHUNK / 256; ++i) {
        int li = i * 256 + t;
        keys[i] = 0xffffffffu;
        if (li < nE) {
            int e = e0 + li;
            unsigned s = (unsigned)ei[e];
            unsigned d = (unsigned)ei[NE + e];
            if (s < NN && d < NN) {
                keys[i] = d >> BINSH;
                packs[i] = (s << BINSH) | (d & ((1u << BINSH) - 1));
                atomicAdd(&hist[keys[i]], 1);
            }
        }
    }
    __syncthreads();
    if (t == 0) { int a = 0; for (int b = 0; b < NBINS; ++b) { base[b] = a; a += hist[b]; } }
    __syncthreads();
    if (t < NBINS) {
        cur[t] = base[t];
        if (hist[t] > 0) gbase[t] = atomicAdd(&cursor[t], hist[t]);
    }
    __syncthreads();
    #pragma unroll
    for (int i = 0; i < CHUNK / 256; ++i) {
        if (keys[i] != 0xffffffffu) {
            int p = atomicAdd(&cur[keys[i]], 1);
            stage[p] = packs[i];
            sbin[p] = (unsigned char)keys[i];
        }
    }
    __syncthreads();
    int tot = cur[NBINS - 1];   // == number of valid edges staged
    for (int j = t; j < tot; j += 256) {
        unsigned b = sbin[j];
        binned[gbase[b] + (j - base[b])] = stage[j];
    }
}

// ---------------- pass 2: per-bin sort -> CSR (u16 src), deg/dinv/rowstart ----------------
__global__ __launch_bounds__(256) void k_csr(
        const unsigned* __restrict__ binned, const int* __restrict__ cursor,
        unsigned short* __restrict__ csr, int* __restrict__ rowstart,
        int* __restrict__ degi, float* __restrict__ dinv) {
    __shared__ unsigned ent[MAXBIN];
    __shared__ unsigned short outv[MAXBIN];
    __shared__ int hist[512], rs[512], cur[512];
    __shared__ int sizes[NBINS];
    int t = threadIdx.x, b = blockIdx.x;

    if (t < NBINS) sizes[t] = cursor[t] - t * BINCAP;
    __syncthreads();
    int bsize = sizes[b]; if (bsize > MAXBIN) bsize = MAXBIN;
    int bstart = 0;
    for (int i = 0; i < b; ++i) bstart += sizes[i];

    for (int j = t; j < bsize; j += 256) ent[j] = binned[b * BINCAP + j];
    for (int k = t; k < 512; k += 256) hist[k] = 0;
    __syncthreads();
    for (int j = t; j < bsize; j += 256) atomicAdd(&hist[ent[j] & 511], 1);
    __syncthreads();
    if (t == 0) { int a = 0; for (int k = 0; k < 512; ++k) { rs[k] = a; a += hist[k]; } }
    __syncthreads();
    for (int k = t; k < 512; k += 256) {
        cur[k] = rs[k];
        int g = (b << BINSH) + k;
        if (g < NN) {
            rowstart[g] = bstart + rs[k];
            degi[g] = hist[k];
            dinv[g] = rsqrtf((float)(hist[k] + 1));
        }
    }
    __syncthreads();
    for (int j = t; j < bsize; j += 256) {
        unsigned v = ent[j];
        int p = atomicAdd(&cur[v & 511], 1);
        outv[p] = (unsigned short)(v >> BINSH);
    }
    __syncthreads();
    for (int j = t; j < bsize; j += 256) csr[bstart + j] = outv[j];
}

// ---------------- MFMA GEMM: ybf = bf16((x @ W) * dinv[n]) ----------------
// 64 rows/block, 4 waves (16 rows each). x split hi/lo bf16 (2 passes) @ bf16 W.
// B-frag pattern = verified m92 B^T layout: b[j] = Wt[col][k0+j], ds_read_b128.
__global__ __launch_bounds__(256) void k_gemm_xw(
        const float* __restrict__ x, const float* __restrict__ W,
        const float* __restrict__ dinv, unsigned short* __restrict__ ybf) {
    __shared__ unsigned short Wt[HD * WPAD];    // W^T bf16, 34.8 KB
    int t = threadIdx.x;
    int rowBase = blockIdx.x * 64;

    // stage W transposed as bf16
    #pragma unroll
    for (int i = 0; i < 16; ++i) {
        int f = t + i * 256;                 // float4 index
        float4 v = ((const float4*)W)[f];
        int h = f >> 5, c0 = (f & 31) * 4;
        Wt[(c0 + 0) * WPAD + h] = f2bf(v.x);
        Wt[(c0 + 1) * WPAD + h] = f2bf(v.y);
        Wt[(c0 + 2) * WPAD + h] = f2bf(v.z);
        Wt[(c0 + 3) * WPAD + h] = f2bf(v.w);
    }
    __syncthreads();

    int w = t >> 6, lane = t & 63;
    int row = rowBase + w * 16 + (lane & 15);
    int rowc = row < NN ? row : NN - 1;
    int kbase = (lane >> 4) * 8;

    // A-frags from global, hi/lo split
    bf16x8 ah[4], al[4];
    const float* xrow = &x[(size_t)rowc * HD];
    #pragma unroll
    for (int kk = 0; kk < 4; ++kk) {
        float4 u0 = *(const float4*)(xrow + kk * 32 + kbase);
        float4 u1 = *(const float4*)(xrow + kk * 32 + kbase + 4);
        float vv[8] = {u0.x, u0.y, u0.z, u0.w, u1.x, u1.y, u1.z, u1.w};
        #pragma unroll
        for (int j = 0; j < 8; ++j) {
            unsigned short hh, ll; split2(vv[j], &hh, &ll);
            ah[kk][j] = (short)hh; al[kk][j] = (short)ll;
        }
    }

    f32x4 acc[8];
    #pragma unroll
    for (int ct = 0; ct < 8; ++ct) acc[ct] = (f32x4){0.f, 0.f, 0.f, 0.f};
    #pragma unroll
    for (int kk = 0; kk < 4; ++kk) {
        #pragma unroll
        for (int ct = 0; ct < 8; ++ct) {
            bf16x8 bfr = *(const bf16x8*)&Wt[(ct * 16 + (lane & 15)) * WPAD + kk * 32 + kbase];
            acc[ct] = __builtin_amdgcn_mfma_f32_16x16x32_bf16(ah[kk], bfr, acc[ct], 0, 0, 0);
            acc[ct] = __builtin_amdgcn_mfma_f32_16x16x32_bf16(al[kk], bfr, acc[ct], 0, 0, 0);
        }
    }

    // epilogue: C layout col=lane&15, row=(lane>>4)*4+reg
    int r0 = rowBase + w * 16 + ((lane >> 4) << 2);
    #pragma unroll
    for (int r = 0; r < 4; ++r) {
        int gr = r0 + r;
        if (gr >= NN) continue;
        float dvv = dinv[gr];
        size_t basei = (size_t)gr * HD;
        #pragma unroll
        for (int ct = 0; ct < 8; ++ct)
            ybf[basei + ct * 16 + (lane & 15)] = f2bf(acc[ct][r] * dvv);
    }
}

// ---------------- gather: z[n] = dinv[n]*(y[n] + sum y[src]) + b ----------------
__global__ __launch_bounds__(256) void k_gather(
        const unsigned short* __restrict__ csr, const int* __restrict__ rowstart,
        const int* __restrict__ degi, const float* __restrict__ dinv,
        const unsigned short* __restrict__ ybf, const float* __restrict__ b,
        float* __restrict__ z) {
    int t = threadIdx.x;
    int n = blockIdx.x * 8 + (t >> 5);
    int lane = t & 31;
    if (n >= NN) return;
    int c = lane * 4;

    float4 acc = ld_bf4(&ybf[(size_t)n * HD + c]);   // self-loop term
    int beg = rowstart[n];
    int dg = degi[n];

    int i = 0;
    for (; i + 4 <= dg; i += 4) {
        int s0 = csr[beg + i + 0];
        int s1 = csr[beg + i + 1];
        int s2 = csr[beg + i + 2];
        int s3 = csr[beg + i + 3];
        float4 v0 = ld_bf4(&ybf[(size_t)s0 * HD + c]);
        float4 v1 = ld_bf4(&ybf[(size_t)s1 * HD + c]);
        float4 v2 = ld_bf4(&ybf[(size_t)s2 * HD + c]);
        float4 v3 = ld_bf4(&ybf[(size_t)s3 * HD + c]);
        acc.x += v0.x + v1.x + v2.x + v3.x;
        acc.y += v0.y + v1.y + v2.y + v3.y;
        acc.z += v0.z + v1.z + v2.z + v3.z;
        acc.w += v0.w + v1.w + v2.w + v3.w;
    }
    for (; i < dg; ++i) {
        int s = csr[beg + i];
        float4 v = ld_bf4(&ybf[(size_t)s * HD + c]);
        acc.x += v.x; acc.y += v.y; acc.z += v.z; acc.w += v.w;
    }

    float dv = dinv[n];
    float4 bv = *(const float4*)&b[c];
    acc.x = acc.x * dv + bv.x;
    acc.y = acc.y * dv + bv.y;
    acc.z = acc.z * dv + bv.z;
    acc.w = acc.w * dv + bv.w;
    *(float4*)&z[(size_t)n * HD + c] = acc;
}

// ---------------- MFMA bilinear: t = z@Wb (3-pass hi/lo); pos=<t,z>, neg=<t,z[perm]> ----------------
__global__ __launch_bounds__(256) void k_bilinear(
        const float* __restrict__ z, const float* __restrict__ Wb,
        const float* __restrict__ bb, const int* __restrict__ perm,
        float* __restrict__ out) {
    __shared__ unsigned short Wth[HD * WPAD];   // Wb^T hi, 34.8 KB
    __shared__ unsigned short Wtl[HD * WPAD];   // Wb^T lo, 34.8 KB
    int t = threadIdx.x;
    int rowBase = blockIdx.x * 64;

    #pragma unroll
    for (int i = 0; i < 16; ++i) {
        int f = t + i * 256;
        float4 v = ((const float4*)Wb)[f];
        int h = f >> 5, c0 = (f & 31) * 4;
        unsigned short hh, ll;
        split2(v.x, &hh, &ll); Wth[(c0 + 0) * WPAD + h] = hh; Wtl[(c0 + 0) * WPAD + h] = ll;
        split2(v.y, &hh, &ll); Wth[(c0 + 1) * WPAD + h] = hh; Wtl[(c0 + 1) * WPAD + h] = ll;
        split2(v.z, &hh, &ll); Wth[(c0 + 2) * WPAD + h] = hh; Wtl[(c0 + 2) * WPAD + h] = ll;
        split2(v.w, &hh, &ll); Wth[(c0 + 3) * WPAD + h] = hh; Wtl[(c0 + 3) * WPAD + h] = ll;
    }
    __syncthreads();

    int w = t >> 6, lane = t & 63;
    int row = rowBase + w * 16 + (lane & 15);
    int rowc = row < NN ? row : NN - 1;
    int kbase = (lane >> 4) * 8;

    bf16x8 zh[4], zl[4];
    const float* zrow = &z[(size_t)rowc * HD];
    #pragma unroll
    for (int kk = 0; kk < 4; ++kk) {
        float4 u0 = *(const float4*)(zrow + kk * 32 + kbase);
        float4 u1 = *(const float4*)(zrow + kk * 32 + kbase + 4);
        float vv[8] = {u0.x, u0.y, u0.z, u0.w, u1.x, u1.y, u1.z, u1.w};
        #pragma unroll
        for (int j = 0; j < 8; ++j) {
            unsigned short hh, ll; split2(vv[j], &hh, &ll);
            zh[kk][j] = (short)hh; zl[kk][j] = (short)ll;
        }
    }

    f32x4 acc[8];
    #pragma unroll
    for (int ct = 0; ct < 8; ++ct) acc[ct] = (f32x4){0.f, 0.f, 0.f, 0.f};
    #pragma unroll
    for (int kk = 0; kk < 4; ++kk) {
        #pragma unroll
        for (int ct = 0; ct < 8; ++ct) {
            int o = (ct * 16 + (lane & 15)) * WPAD + kk * 32 + kbase;
            bf16x8 bh = *(const bf16x8*)&Wth[o];
            bf16x8 bl = *(const bf16x8*)&Wtl[o];
            acc[ct] = __builtin_amdgcn_mfma_f32_16x16x32_bf16(zh[kk], bh, acc[ct], 0, 0, 0);
            acc[ct] = __builtin_amdgcn_mfma_f32_16x16x32_bf16(zl[kk], bh, acc[ct], 0, 0, 0);
            acc[ct] = __builtin_amdgcn_mfma_f32_16x16x32_bf16(zh[kk], bl, acc[ct], 0, 0, 0);
        }
    }

    // epilogue: per-row dot with z and z[perm] in f32
    float bbv = bb[0];
    int r0 = rowBase + w * 16 + ((lane >> 4) << 2);
    float pos[4] = {0.f, 0.f, 0.f, 0.f}, neg[4] = {0.f, 0.f, 0.f, 0.f};
    #pragma unroll
    for (int r = 0; r < 4; ++r) {
        int gr = (r0 + r < NN) ? r0 + r : NN - 1;
        int pr = perm[gr];
        const float* zr = &z[(size_t)gr * HD];
        const float* zp = &z[(size_t)pr * HD];
        #pragma unroll
        for (int ct = 0; ct < 8; ++ct) {
            float tv = acc[ct][r];
            int col = ct * 16 + (lane & 15);
            pos[r] += tv * zr[col];
            neg[r] += tv * zp[col];
        }
    }
    #pragma unroll
    for (int r = 0; r < 4; ++r) {
        #pragma unroll
        for (int off = 1; off < 16; off <<= 1) {
            pos[r] += __shfl_xor(pos[r], off);
            neg[r] += __shfl_xor(neg[r], off);
        }
    }
    if ((lane & 15) == 0) {
        #pragma unroll
        for (int r = 0; r < 4; ++r) {
            int gr = r0 + r;
            if (gr < NN) {
                out[gr] = pos[r] + bbv;
                out[NN + gr] = neg[r] + bbv;
            }
        }
    }
}

extern "C" void kernel_launch(void* const* d_in, const int* in_sizes, int n_in,
                              void* d_out, int out_size, void* d_ws, size_t ws_size,
                              hipStream_t stream) {
    const float* x    = (const float*)d_in[0];
    const float* W    = (const float*)d_in[1];
    const float* b    = (const float*)d_in[2];
    const float* Wb   = (const float*)d_in[3];
    const float* bb   = (const float*)d_in[4];
    const int*   ei   = (const int*)d_in[5];
    const int*   perm = (const int*)d_in[6];
    float* out = (float*)d_out;

    char* ws = (char*)d_ws;
    int*            cursor   = (int*)(ws + 0);               // 4 KB
    float*          dinv     = (float*)(ws + 0x1000);        // 200 KB
    int*            rowstart = (int*)(ws + 0x33000);         // 200 KB
    int*            degi     = (int*)(ws + 0x65000);         // 200 KB
    unsigned short* csr      = (unsigned short*)(ws + 0x97000);   // 1.6 MB
    unsigned*       binned   = (unsigned*)(ws + 0x240000);   // 3.6 MB
    unsigned short* ybf      = (unsigned short*)(ws + 0x600000);  // 12.8 MB
    float*          z        = (float*)(ws + 0x2000000);     // 25.6 MB

    k_init<<<1, 128, 0, stream>>>(cursor);
    k_binplace<<<(NE + CHUNK - 1) / CHUNK, 256, 0, stream>>>(ei, cursor, binned);
    k_csr<<<NBINS, 256, 0, stream>>>(binned, cursor, csr, rowstart, degi, dinv);
    k_gemm_xw<<<(NN + 63) / 64, 256, 0, stream>>>(x, W, dinv, ybf);
    k_gather<<<(NN + 7) / 8, 256, 0, stream>>>(csr, rowstart, degi, dinv, ybf, b, z);
    k_bilinear<<<(NN + 63) / 64, 256, 0, stream>>>(z, Wb, bb, perm, out);
}

// Round 8
// 98.554 us; speedup vs baseline: 1.8408x; 1.3712x over previous
//
#include <hip/hip_runtime.h>
#include <hip/hip_bf16.h>

#define NN 50000
#define NE 800000
#define HD 128
#define WPAD 136                // transposed-W LDS/global row stride (shorts), 16B-aligned

#define BINSH 9                 // 512 nodes per coarse bin
#define NBINS 98                // ceil(50000/512)
#define BINCAP 9216             // slop capacity (mean 8163, 11.6 sigma)
#define CHUNK 1024              // edges per binplace block (782 blocks)
#define MAXBIN 9216

#define GEMM_BLOCKS ((NN + 63) / 64)          // 782
#define BIN_BLOCKS  ((NE + CHUNK - 1) / CHUNK) // 782

typedef __attribute__((ext_vector_type(8))) short bf16x8;
typedef __attribute__((ext_vector_type(4))) float f32x4;

// f32 -> bf16 round-to-nearest-even
__device__ inline unsigned short f2bf(float f) {
    union { float f; unsigned u; } c; c.f = f;
    unsigned r = c.u + 0x7fff + ((c.u >> 16) & 1);
    return (unsigned short)(r >> 16);
}

__device__ inline float bflo(unsigned u) { return __uint_as_float(u << 16); }
__device__ inline float bfhi(unsigned u) { return __uint_as_float(u & 0xffff0000u); }

// split f32 into hi bf16 + lo bf16 (residual)
__device__ inline void split2(float v, unsigned short* h, unsigned short* l) {
    unsigned short hh = f2bf(v);
    float fh = __uint_as_float(((unsigned)hh) << 16);
    *h = hh;
    *l = f2bf(v - fh);
}

// load 4 bf16 (8B) -> float4
__device__ inline float4 ld_bf4(const unsigned short* p) {
    uint2 q = *(const uint2*)p;
    float4 r;
    r.x = bflo(q.x); r.y = bfhi(q.x);
    r.z = bflo(q.y); r.w = bfhi(q.y);
    return r;
}

// ---------------- prep: cursor init + W^T bf16 + Wb^T hi/lo bf16 tables ----------------
__global__ __launch_bounds__(256) void k_prep(
        const float* __restrict__ W, const float* __restrict__ Wb, int* cursor,
        unsigned short* __restrict__ Wtg,
        unsigned short* __restrict__ Wbth, unsigned short* __restrict__ Wbtl) {
    int t = threadIdx.x;
    if (blockIdx.x == 0 && t < NBINS) cursor[t] = t * BINCAP;
    int idx = blockIdx.x * 256 + t;
    if (idx < HD * HD) {
        int h = idx >> 7, c = idx & 127;        // W[h][c]
        Wtg[c * WPAD + h] = f2bf(W[idx]);
        unsigned short hh, ll; split2(Wb[idx], &hh, &ll);
        Wbth[c * WPAD + h] = hh;
        Wbtl[c * WPAD + h] = ll;
    }
}

// ---------------- fused: blocks [0,782) MFMA GEMM, blocks [782,1564) edge binning ----------------
__global__ __launch_bounds__(256) void k_fused1(
        const float* __restrict__ x, const unsigned short* __restrict__ Wtg,
        unsigned short* __restrict__ ybf,
        const int* __restrict__ ei, int* cursor, unsigned* __restrict__ binned) {
    __shared__ union {
        unsigned short Wt[HD * WPAD];           // 34816 B
        struct {
            unsigned stage[CHUNK];
            unsigned char sbin[CHUNK];
            int hist[NBINS], base[NBINS], cur[NBINS], gbase[NBINS];
        } p;
    } sh;
    int t = threadIdx.x;

    if (blockIdx.x < GEMM_BLOCKS) {
        // ---- GEMM: ybf = bf16(x @ W)  (dinv applied later in gather) ----
        int rowBase = blockIdx.x * 64;
        const uint4* src = (const uint4*)Wtg;
        uint4* dst = (uint4*)sh.Wt;
        #pragma unroll
        for (int i = 0; i < 9; ++i) {
            int f = t + i * 256;
            if (f < (HD * WPAD * 2) / 16) dst[f] = src[f];
        }
        __syncthreads();

        int w = t >> 6, lane = t & 63;
        int row = rowBase + w * 16 + (lane & 15);
        int rowc = row < NN ? row : NN - 1;
        int kbase = (lane >> 4) * 8;

        bf16x8 ah[4], al[4];
        const float* xrow = &x[(size_t)rowc * HD];
        #pragma unroll
        for (int kk = 0; kk < 4; ++kk) {
            float4 u0 = *(const float4*)(xrow + kk * 32 + kbase);
            float4 u1 = *(const float4*)(xrow + kk * 32 + kbase + 4);
            float vv[8] = {u0.x, u0.y, u0.z, u0.w, u1.x, u1.y, u1.z, u1.w};
            #pragma unroll
            for (int j = 0; j < 8; ++j) {
                unsigned short hh, ll; split2(vv[j], &hh, &ll);
                ah[kk][j] = (short)hh; al[kk][j] = (short)ll;
            }
        }

        f32x4 acc[8];
        #pragma unroll
        for (int ct = 0; ct < 8; ++ct) acc[ct] = (f32x4){0.f, 0.f, 0.f, 0.f};
        #pragma unroll
        for (int kk = 0; kk < 4; ++kk) {
            #pragma unroll
            for (int ct = 0; ct < 8; ++ct) {
                bf16x8 bfr = *(const bf16x8*)&sh.Wt[(ct * 16 + (lane & 15)) * WPAD + kk * 32 + kbase];
                acc[ct] = __builtin_amdgcn_mfma_f32_16x16x32_bf16(ah[kk], bfr, acc[ct], 0, 0, 0);
                acc[ct] = __builtin_amdgcn_mfma_f32_16x16x32_bf16(al[kk], bfr, acc[ct], 0, 0, 0);
            }
        }

        int r0 = rowBase + w * 16 + ((lane >> 4) << 2);
        #pragma unroll
        for (int r = 0; r < 4; ++r) {
            int gr = r0 + r;
            if (gr >= NN) continue;
            size_t basei = (size_t)gr * HD;
            #pragma unroll
            for (int ct = 0; ct < 8; ++ct)
                ybf[basei + ct * 16 + (lane & 15)] = f2bf(acc[ct][r]);
        }
    } else {
        // ---- binplace: bin edges by dst>>9, coalesced writes ----
        int e0 = (blockIdx.x - GEMM_BLOCKS) * CHUNK;
        int nE = NE - e0; if (nE > CHUNK) nE = CHUNK;

        if (t < NBINS) sh.p.hist[t] = 0;
        __syncthreads();

        unsigned keys[CHUNK / 256], packs[CHUNK / 256];
        #pragma unroll
        for (int i = 0; i < CHUNK / 256; ++i) {
            int li = i * 256 + t;
            keys[i] = 0xffffffffu;
            if (li < nE) {
                int e = e0 + li;
                unsigned s = (unsigned)ei[e];
                unsigned d = (unsigned)ei[NE + e];
                if (s < NN && d < NN) {
                    keys[i] = d >> BINSH;
                    packs[i] = (s << BINSH) | (d & ((1u << BINSH) - 1));
                    atomicAdd(&sh.p.hist[keys[i]], 1);
                }
            }
        }
        __syncthreads();
        if (t == 0) { int a = 0; for (int b = 0; b < NBINS; ++b) { sh.p.base[b] = a; a += sh.p.hist[b]; } }
        __syncthreads();
        if (t < NBINS) {
            sh.p.cur[t] = sh.p.base[t];
            if (sh.p.hist[t] > 0) sh.p.gbase[t] = atomicAdd(&cursor[t], sh.p.hist[t]);
        }
        __syncthreads();
        #pragma unroll
        for (int i = 0; i < CHUNK / 256; ++i) {
            if (keys[i] != 0xffffffffu) {
                int p = atomicAdd(&sh.p.cur[keys[i]], 1);
                sh.p.stage[p] = packs[i];
                sh.p.sbin[p] = (unsigned char)keys[i];
            }
        }
        __syncthreads();
        int tot = sh.p.cur[NBINS - 1];
        for (int j = t; j < tot; j += 256) {
            unsigned b = sh.p.sbin[j];
            binned[sh.p.gbase[b] + (j - sh.p.base[b])] = sh.p.stage[j];
        }
    }
}

// ---------------- pass 2: per-bin sort -> CSR (u16 src), deg/dinv/rowstart ----------------
__global__ __launch_bounds__(256) void k_csr(
        const unsigned* __restrict__ binned, const int* __restrict__ cursor,
        unsigned short* __restrict__ csr, int* __restrict__ rowstart,
        int* __restrict__ degi, float* __restrict__ dinv) {
    __shared__ unsigned ent[MAXBIN];
    __shared__ unsigned short outv[MAXBIN];
    __shared__ int hist[512], rs[512], cur[512];
    __shared__ int sizes[NBINS];
    int t = threadIdx.x, b = blockIdx.x;

    if (t < NBINS) sizes[t] = cursor[t] - t * BINCAP;
    __syncthreads();
    int bsize = sizes[b]; if (bsize > MAXBIN) bsize = MAXBIN;
    int bstart = 0;
    for (int i = 0; i < b; ++i) bstart += sizes[i];

    for (int j = t; j < bsize; j += 256) ent[j] = binned[b * BINCAP + j];
    for (int k = t; k < 512; k += 256) hist[k] = 0;
    __syncthreads();
    for (int j = t; j < bsize; j += 256) atomicAdd(&hist[ent[j] & 511], 1);
    __syncthreads();
    if (t == 0) { int a = 0; for (int k = 0; k < 512; ++k) { rs[k] = a; a += hist[k]; } }
    __syncthreads();
    for (int k = t; k < 512; k += 256) {
        cur[k] = rs[k];
        int g = (b << BINSH) + k;
        if (g < NN) {
            rowstart[g] = bstart + rs[k];
            degi[g] = hist[k];
            dinv[g] = rsqrtf((float)(hist[k] + 1));
        }
    }
    __syncthreads();
    for (int j = t; j < bsize; j += 256) {
        unsigned v = ent[j];
        int p = atomicAdd(&cur[v & 511], 1);
        outv[p] = (unsigned short)(v >> BINSH);
    }
    __syncthreads();
    for (int j = t; j < bsize; j += 256) csr[bstart + j] = outv[j];
}

// ---------------- gather: z[n] = dinv[n]*(y[n]*dinv[n] + sum y[s]*dinv[s]) + b ----------------
__global__ __launch_bounds__(256) void k_gather(
        const unsigned short* __restrict__ csr, const int* __restrict__ rowstart,
        const int* __restrict__ degi, const float* __restrict__ dinv,
        const unsigned short* __restrict__ ybf, const float* __restrict__ b,
        float* __restrict__ z) {
    int t = threadIdx.x;
    int n = blockIdx.x * 8 + (t >> 5);
    int lane = t & 31;
    if (n >= NN) return;
    int c = lane * 4;

    float dvn = dinv[n];
    float4 self = ld_bf4(&ybf[(size_t)n * HD + c]);
    float4 acc;
    acc.x = self.x * dvn; acc.y = self.y * dvn;
    acc.z = self.z * dvn; acc.w = self.w * dvn;
    int beg = rowstart[n];
    int dg = degi[n];

    int i = 0;
    for (; i + 4 <= dg; i += 4) {
        int s0 = csr[beg + i + 0];
        int s1 = csr[beg + i + 1];
        int s2 = csr[beg + i + 2];
        int s3 = csr[beg + i + 3];
        float d0 = dinv[s0], d1 = dinv[s1], d2 = dinv[s2], d3 = dinv[s3];
        float4 v0 = ld_bf4(&ybf[(size_t)s0 * HD + c]);
        float4 v1 = ld_bf4(&ybf[(size_t)s1 * HD + c]);
        float4 v2 = ld_bf4(&ybf[(size_t)s2 * HD + c]);
        float4 v3 = ld_bf4(&ybf[(size_t)s3 * HD + c]);
        acc.x += v0.x * d0 + v1.x * d1 + v2.x * d2 + v3.x * d3;
        acc.y += v0.y * d0 + v1.y * d1 + v2.y * d2 + v3.y * d3;
        acc.z += v0.z * d0 + v1.z * d1 + v2.z * d2 + v3.z * d3;
        acc.w += v0.w * d0 + v1.w * d1 + v2.w * d2 + v3.w * d3;
    }
    for (; i < dg; ++i) {
        int s = csr[beg + i];
        float ds = dinv[s];
        float4 v = ld_bf4(&ybf[(size_t)s * HD + c]);
        acc.x += v.x * ds; acc.y += v.y * ds;
        acc.z += v.z * ds; acc.w += v.w * ds;
    }

    float4 bv = *(const float4*)&b[c];
    acc.x = acc.x * dvn + bv.x;
    acc.y = acc.y * dvn + bv.y;
    acc.z = acc.z * dvn + bv.z;
    acc.w = acc.w * dvn + bv.w;
    *(float4*)&z[(size_t)n * HD + c] = acc;
}

// ---------------- MFMA bilinear: t = z@Wb (3-pass hi/lo); pos=<t,z>, neg=<t,z[perm]> ----------------
__global__ __launch_bounds__(256) void k_bilinear(
        const float* __restrict__ z,
        const unsigned short* __restrict__ Wbth, const unsigned short* __restrict__ Wbtl,
        const float* __restrict__ bb, const int* __restrict__ perm,
        float* __restrict__ out) {
    __shared__ unsigned short Wth[HD * WPAD];   // Wb^T hi, 34.8 KB
    __shared__ unsigned short Wtl[HD * WPAD];   // Wb^T lo, 34.8 KB
    int t = threadIdx.x;
    int rowBase = blockIdx.x * 64;

    {
        const uint4* sh = (const uint4*)Wbth;
        const uint4* sl = (const uint4*)Wbtl;
        uint4* dh = (uint4*)Wth;
        uint4* dl = (uint4*)Wtl;
        #pragma unroll
        for (int i = 0; i < 9; ++i) {
            int f = t + i * 256;
            if (f < (HD * WPAD * 2) / 16) { dh[f] = sh[f]; dl[f] = sl[f]; }
        }
    }
    __syncthreads();

    int w = t >> 6, lane = t & 63;
    int row = rowBase + w * 16 + (lane & 15);
    int rowc = row < NN ? row : NN - 1;
    int kbase = (lane >> 4) * 8;

    bf16x8 zh[4], zl[4];
    const float* zrow = &z[(size_t)rowc * HD];
    #pragma unroll
    for (int kk = 0; kk < 4; ++kk) {
        float4 u0 = *(const float4*)(zrow + kk * 32 + kbase);
        float4 u1 = *(const float4*)(zrow + kk * 32 + kbase + 4);
        float vv[8] = {u0.x, u0.y, u0.z, u0.w, u1.x, u1.y, u1.z, u1.w};
        #pragma unroll
        for (int j = 0; j < 8; ++j) {
            unsigned short hh, ll; split2(vv[j], &hh, &ll);
            zh[kk][j] = (short)hh; zl[kk][j] = (short)ll;
        }
    }

    f32x4 acc[8];
    #pragma unroll
    for (int ct = 0; ct < 8; ++ct) acc[ct] = (f32x4){0.f, 0.f, 0.f, 0.f};
    #pragma unroll
    for (int kk = 0; kk < 4; ++kk) {
        #pragma unroll
        for (int ct = 0; ct < 8; ++ct) {
            int o = (ct * 16 + (lane & 15)) * WPAD + kk * 32 + kbase;
            bf16x8 bh = *(const bf16x8*)&Wth[o];
            bf16x8 bl = *(const bf16x8*)&Wtl[o];
            acc[ct] = __builtin_amdgcn_mfma_f32_16x16x32_bf16(zh[kk], bh, acc[ct], 0, 0, 0);
            acc[ct] = __builtin_amdgcn_mfma_f32_16x16x32_bf16(zl[kk], bh, acc[ct], 0, 0, 0);
            acc[ct] = __builtin_amdgcn_mfma_f32_16x16x32_bf16(zh[kk], bl, acc[ct], 0, 0, 0);
        }
    }

    float bbv = bb[0];
    int r0 = rowBase + w * 16 + ((lane >> 4) << 2);
    float pos[4] = {0.f, 0.f, 0.f, 0.f}, neg[4] = {0.f, 0.f, 0.f, 0.f};
    #pragma unroll
    for (int r = 0; r < 4; ++r) {
        int gr = (r0 + r < NN) ? r0 + r : NN - 1;
        int pr = perm[gr];
        const float* zr = &z[(size_t)gr * HD];
        const float* zp = &z[(size_t)pr * HD];
        #pragma unroll
        for (int ct = 0; ct < 8; ++ct) {
            float tv = acc[ct][r];
            int col = ct * 16 + (lane & 15);
            pos[r] += tv * zr[col];
            neg[r] += tv * zp[col];
        }
    }
    #pragma unroll
    for (int r = 0; r < 4; ++r) {
        #pragma unroll
        for (int off = 1; off < 16; off <<= 1) {
            pos[r] += __shfl_xor(pos[r], off);
            neg[r] += __shfl_xor(neg[r], off);
        }
    }
    if ((lane & 15) == 0) {
        #pragma unroll
        for (int r = 0; r < 4; ++r) {
            int gr = r0 + r;
            if (gr < NN) {
                out[gr] = pos[r] + bbv;
                out[NN + gr] = neg[r] + bbv;
            }
        }
    }
}

extern "C" void kernel_launch(void* const* d_in, const int* in_sizes, int n_in,
                              void* d_out, int out_size, void* d_ws, size_t ws_size,
                              hipStream_t stream) {
    const float* x    = (const float*)d_in[0];
    const float* W    = (const float*)d_in[1];
    const float* b    = (const float*)d_in[2];
    const float* Wb   = (const float*)d_in[3];
    const float* bb   = (const float*)d_in[4];
    const int*   ei   = (const int*)d_in[5];
    const int*   perm = (const int*)d_in[6];
    float* out = (float*)d_out;

    char* ws = (char*)d_ws;
    int*            cursor   = (int*)(ws + 0);               // 4 KB
    float*          dinv     = (float*)(ws + 0x1000);        // 200 KB
    int*            rowstart = (int*)(ws + 0x33000);         // 200 KB
    int*            degi     = (int*)(ws + 0x65000);         // 200 KB
    unsigned short* csr      = (unsigned short*)(ws + 0x97000);   // 1.6 MB
    unsigned*       binned   = (unsigned*)(ws + 0x240000);   // 3.6 MB
    unsigned short* Wtg      = (unsigned short*)(ws + 0x5B0000);  // 35 KB
    unsigned short* Wbth     = (unsigned short*)(ws + 0x5C0000);  // 35 KB
    unsigned short* Wbtl     = (unsigned short*)(ws + 0x5D0000);  // 35 KB
    unsigned short* ybf      = (unsigned short*)(ws + 0x600000);  // 12.8 MB
    float*          z        = (float*)(ws + 0x2000000);     // 25.6 MB

    k_prep<<<(HD * HD + 255) / 256, 256, 0, stream>>>(W, Wb, cursor, Wtg, Wbth, Wbtl);
    k_fused1<<<GEMM_BLOCKS + BIN_BLOCKS, 256, 0, stream>>>(x, Wtg, ybf, ei, cursor, binned);
    k_csr<<<NBINS, 256, 0, stream>>>(binned, cursor, csr, rowstart, degi, dinv);
    k_gather<<<(NN + 7) / 8, 256, 0, stream>>>(csr, rowstart, degi, dinv, ybf, b, z);
    k_bilinear<<<GEMM_BLOCKS, 256, 0, stream>>>(z, Wbth, Wbtl, bb, perm, out);
}

// Round 9
// 95.058 us; speedup vs baseline: 1.9085x; 1.0368x over previous
//
#include <hip/hip_runtime.h>
#include <hip/hip_bf16.h>

#define NN 50000
#define NE 800000
#define HD 128
#define WPAD 136                // transposed-W LDS/global row stride (shorts), 16B-aligned

#define BINSH 9                 // 512 nodes per coarse bin
#define NBINS 98                // ceil(50000/512)
#define BINCAP 9216             // slop capacity (mean 8163, 11.6 sigma)
#define CHUNK 1024              // edges per binplace block (782 blocks)
#define MAXBIN 9216

#define GEMM_BLOCKS ((NN + 63) / 64)          // 782
#define BIN_BLOCKS  ((NE + CHUNK - 1) / CHUNK) // 782

typedef __attribute__((ext_vector_type(8))) short bf16x8;
typedef __attribute__((ext_vector_type(4))) float f32x4;

// f32 -> bf16 round-to-nearest-even
__device__ inline unsigned short f2bf(float f) {
    union { float f; unsigned u; } c; c.f = f;
    unsigned r = c.u + 0x7fff + ((c.u >> 16) & 1);
    return (unsigned short)(r >> 16);
}

__device__ inline float bflo(unsigned u) { return __uint_as_float(u << 16); }
__device__ inline float b2f(unsigned short u) { return __uint_as_float(((unsigned)u) << 16); }
__device__ inline float bfhi(unsigned u) { return __uint_as_float(u & 0xffff0000u); }

// split f32 into hi bf16 + lo bf16 (residual)
__device__ inline void split2(float v, unsigned short* h, unsigned short* l) {
    unsigned short hh = f2bf(v);
    float fh = __uint_as_float(((unsigned)hh) << 16);
    *h = hh;
    *l = f2bf(v - fh);
}

// load 4 bf16 (8B) -> float4
__device__ inline float4 ld_bf4(const unsigned short* p) {
    uint2 q = *(const uint2*)p;
    float4 r;
    r.x = bflo(q.x); r.y = bfhi(q.x);
    r.z = bflo(q.y); r.w = bfhi(q.y);
    return r;
}

// ---------------- prep: cursor init + W^T bf16 + Wb^T hi/lo bf16 tables ----------------
__global__ __launch_bounds__(256) void k_prep(
        const float* __restrict__ W, const float* __restrict__ Wb, int* cursor,
        unsigned short* __restrict__ Wtg,
        unsigned short* __restrict__ Wbth, unsigned short* __restrict__ Wbtl) {
    int t = threadIdx.x;
    if (blockIdx.x == 0 && t < NBINS) cursor[t] = t * BINCAP;
    int idx = blockIdx.x * 256 + t;
    if (idx < HD * HD) {
        int h = idx >> 7, c = idx & 127;        // W[h][c]
        Wtg[c * WPAD + h] = f2bf(W[idx]);
        unsigned short hh, ll; split2(Wb[idx], &hh, &ll);
        Wbth[c * WPAD + h] = hh;
        Wbtl[c * WPAD + h] = ll;
    }
}

// ---------------- fused: blocks [0,782) MFMA GEMM, blocks [782,1564) edge binning ----------------
__global__ __launch_bounds__(256) void k_fused1(
        const float* __restrict__ x, const unsigned short* __restrict__ Wtg,
        unsigned short* __restrict__ ybf,
        const int* __restrict__ ei, int* cursor, unsigned* __restrict__ binned) {
    __shared__ union {
        unsigned short Wt[HD * WPAD];           // 34816 B
        struct {
            unsigned stage[CHUNK];
            unsigned char sbin[CHUNK];
            int hist[NBINS], base[NBINS], cur[NBINS], gbase[NBINS];
        } p;
    } sh;
    int t = threadIdx.x;

    if (blockIdx.x < GEMM_BLOCKS) {
        // ---- GEMM: ybf = bf16(x @ W)  (dinv applied later in gather) ----
        int rowBase = blockIdx.x * 64;
        const uint4* src = (const uint4*)Wtg;
        uint4* dst = (uint4*)sh.Wt;
        #pragma unroll
        for (int i = 0; i < 9; ++i) {
            int f = t + i * 256;
            if (f < (HD * WPAD * 2) / 16) dst[f] = src[f];
        }
        __syncthreads();

        int w = t >> 6, lane = t & 63;
        int row = rowBase + w * 16 + (lane & 15);
        int rowc = row < NN ? row : NN - 1;
        int kbase = (lane >> 4) * 8;

        bf16x8 ah[4], al[4];
        const float* xrow = &x[(size_t)rowc * HD];
        #pragma unroll
        for (int kk = 0; kk < 4; ++kk) {
            float4 u0 = *(const float4*)(xrow + kk * 32 + kbase);
            float4 u1 = *(const float4*)(xrow + kk * 32 + kbase + 4);
            float vv[8] = {u0.x, u0.y, u0.z, u0.w, u1.x, u1.y, u1.z, u1.w};
            #pragma unroll
            for (int j = 0; j < 8; ++j) {
                unsigned short hh, ll; split2(vv[j], &hh, &ll);
                ah[kk][j] = (short)hh; al[kk][j] = (short)ll;
            }
        }

        f32x4 acc[8];
        #pragma unroll
        for (int ct = 0; ct < 8; ++ct) acc[ct] = (f32x4){0.f, 0.f, 0.f, 0.f};
        #pragma unroll
        for (int kk = 0; kk < 4; ++kk) {
            #pragma unroll
            for (int ct = 0; ct < 8; ++ct) {
                bf16x8 bfr = *(const bf16x8*)&sh.Wt[(ct * 16 + (lane & 15)) * WPAD + kk * 32 + kbase];
                acc[ct] = __builtin_amdgcn_mfma_f32_16x16x32_bf16(ah[kk], bfr, acc[ct], 0, 0, 0);
                acc[ct] = __builtin_amdgcn_mfma_f32_16x16x32_bf16(al[kk], bfr, acc[ct], 0, 0, 0);
            }
        }

        int r0 = rowBase + w * 16 + ((lane >> 4) << 2);
        #pragma unroll
        for (int r = 0; r < 4; ++r) {
            int gr = r0 + r;
            if (gr >= NN) continue;
            size_t basei = (size_t)gr * HD;
            #pragma unroll
            for (int ct = 0; ct < 8; ++ct)
                ybf[basei + ct * 16 + (lane & 15)] = f2bf(acc[ct][r]);
        }
    } else {
        // ---- binplace: bin edges by dst>>9, coalesced writes ----
        int e0 = (blockIdx.x - GEMM_BLOCKS) * CHUNK;
        int nE = NE - e0; if (nE > CHUNK) nE = CHUNK;

        if (t < NBINS) sh.p.hist[t] = 0;
        __syncthreads();

        unsigned keys[CHUNK / 256], packs[CHUNK / 256];
        #pragma unroll
        for (int i = 0; i < CHUNK / 256; ++i) {
            int li = i * 256 + t;
            keys[i] = 0xffffffffu;
            if (li < nE) {
                int e = e0 + li;
                unsigned s = (unsigned)ei[e];
                unsigned d = (unsigned)ei[NE + e];
                if (s < NN && d < NN) {
                    keys[i] = d >> BINSH;
                    packs[i] = (s << BINSH) | (d & ((1u << BINSH) - 1));
                    atomicAdd(&sh.p.hist[keys[i]], 1);
                }
            }
        }
        __syncthreads();
        if (t == 0) { int a = 0; for (int b = 0; b < NBINS; ++b) { sh.p.base[b] = a; a += sh.p.hist[b]; } }
        __syncthreads();
        if (t < NBINS) {
            sh.p.cur[t] = sh.p.base[t];
            if (sh.p.hist[t] > 0) sh.p.gbase[t] = atomicAdd(&cursor[t], sh.p.hist[t]);
        }
        __syncthreads();
        #pragma unroll
        for (int i = 0; i < CHUNK / 256; ++i) {
            if (keys[i] != 0xffffffffu) {
                int p = atomicAdd(&sh.p.cur[keys[i]], 1);
                sh.p.stage[p] = packs[i];
                sh.p.sbin[p] = (unsigned char)keys[i];
            }
        }
        __syncthreads();
        int tot = sh.p.cur[NBINS - 1];
        for (int j = t; j < tot; j += 256) {
            unsigned b = sh.p.sbin[j];
            binned[sh.p.gbase[b] + (j - sh.p.base[b])] = sh.p.stage[j];
        }
    }
}

// ---------------- pass 2: per-bin sort -> CSR (u16 src), deg/dinv/rowstart ----------------
__global__ __launch_bounds__(256) void k_csr(
        const unsigned* __restrict__ binned, const int* __restrict__ cursor,
        unsigned short* __restrict__ csr, int* __restrict__ rowstart,
        int* __restrict__ degi, float* __restrict__ dinv) {
    __shared__ unsigned ent[MAXBIN];
    __shared__ unsigned short outv[MAXBIN];
    __shared__ int hist[512], rs[512], cur[512];
    __shared__ int sizes[NBINS];
    int t = threadIdx.x, b = blockIdx.x;

    if (t < NBINS) sizes[t] = cursor[t] - t * BINCAP;
    __syncthreads();
    int bsize = sizes[b]; if (bsize > MAXBIN) bsize = MAXBIN;
    int bstart = 0;
    for (int i = 0; i < b; ++i) bstart += sizes[i];

    for (int j = t; j < bsize; j += 256) ent[j] = binned[b * BINCAP + j];
    for (int k = t; k < 512; k += 256) hist[k] = 0;
    __syncthreads();
    for (int j = t; j < bsize; j += 256) atomicAdd(&hist[ent[j] & 511], 1);
    __syncthreads();
    if (t == 0) { int a = 0; for (int k = 0; k < 512; ++k) { rs[k] = a; a += hist[k]; } }
    __syncthreads();
    for (int k = t; k < 512; k += 256) {
        cur[k] = rs[k];
        int g = (b << BINSH) + k;
        if (g < NN) {
            rowstart[g] = bstart + rs[k];
            degi[g] = hist[k];
            dinv[g] = rsqrtf((float)(hist[k] + 1));
        }
    }
    __syncthreads();
    for (int j = t; j < bsize; j += 256) {
        unsigned v = ent[j];
        int p = atomicAdd(&cur[v & 511], 1);
        outv[p] = (unsigned short)(v >> BINSH);
    }
    __syncthreads();
    for (int j = t; j < bsize; j += 256) csr[bstart + j] = outv[j];
}

// ---------------- gather: zbf[n] = bf16(dinv[n]*(y[n]*dinv[n] + sum y[s]*dinv[s]) + b) ----------------
__global__ __launch_bounds__(256) void k_gather(
        const unsigned short* __restrict__ csr, const int* __restrict__ rowstart,
        const int* __restrict__ degi, const float* __restrict__ dinv,
        const unsigned short* __restrict__ ybf, const float* __restrict__ b,
        unsigned short* __restrict__ zbf) {
    int t = threadIdx.x;
    int n = blockIdx.x * 8 + (t >> 5);
    int lane = t & 31;
    if (n >= NN) return;
    int c = lane * 4;

    float dvn = dinv[n];
    float4 self = ld_bf4(&ybf[(size_t)n * HD + c]);
    float4 acc;
    acc.x = self.x * dvn; acc.y = self.y * dvn;
    acc.z = self.z * dvn; acc.w = self.w * dvn;
    int beg = rowstart[n];
    int dg = degi[n];

    int i = 0;
    for (; i + 8 <= dg; i += 8) {
        int ss[8];
        #pragma unroll
        for (int u = 0; u < 8; ++u) ss[u] = csr[beg + i + u];
        float dd[8];
        float4 vv[8];
        #pragma unroll
        for (int u = 0; u < 8; ++u) {
            dd[u] = dinv[ss[u]];
            vv[u] = ld_bf4(&ybf[(size_t)ss[u] * HD + c]);
        }
        #pragma unroll
        for (int u = 0; u < 8; ++u) {
            acc.x += vv[u].x * dd[u];
            acc.y += vv[u].y * dd[u];
            acc.z += vv[u].z * dd[u];
            acc.w += vv[u].w * dd[u];
        }
    }
    for (; i < dg; ++i) {
        int s = csr[beg + i];
        float ds = dinv[s];
        float4 v = ld_bf4(&ybf[(size_t)s * HD + c]);
        acc.x += v.x * ds; acc.y += v.y * ds;
        acc.z += v.z * ds; acc.w += v.w * ds;
    }

    float4 bv = *(const float4*)&b[c];
    ushort4 o;
    o.x = f2bf(acc.x * dvn + bv.x);
    o.y = f2bf(acc.y * dvn + bv.y);
    o.z = f2bf(acc.z * dvn + bv.z);
    o.w = f2bf(acc.w * dvn + bv.w);
    *(ushort4*)&zbf[(size_t)n * HD + c] = o;
}

// ---------------- MFMA bilinear: t = zbf@Wb (2-pass Wb hi/lo); pos=<t,z>, neg=<t,z[perm]> ----------------
__global__ __launch_bounds__(256) void k_bilinear(
        const unsigned short* __restrict__ zbf,
        const unsigned short* __restrict__ Wbth, const unsigned short* __restrict__ Wbtl,
        const float* __restrict__ bb, const int* __restrict__ perm,
        float* __restrict__ out) {
    __shared__ unsigned short Wth[HD * WPAD];   // Wb^T hi, 34.8 KB
    __shared__ unsigned short Wtl[HD * WPAD];   // Wb^T lo, 34.8 KB
    int t = threadIdx.x;
    int rowBase = blockIdx.x * 64;

    {
        const uint4* sh = (const uint4*)Wbth;
        const uint4* sl = (const uint4*)Wbtl;
        uint4* dh = (uint4*)Wth;
        uint4* dl = (uint4*)Wtl;
        #pragma unroll
        for (int i = 0; i < 9; ++i) {
            int f = t + i * 256;
            if (f < (HD * WPAD * 2) / 16) { dh[f] = sh[f]; dl[f] = sl[f]; }
        }
    }
    __syncthreads();

    int w = t >> 6, lane = t & 63;
    int row = rowBase + w * 16 + (lane & 15);
    int rowc = row < NN ? row : NN - 1;
    int kbase = (lane >> 4) * 8;

    bf16x8 za[4];
    const unsigned short* zrow = &zbf[(size_t)rowc * HD];
    #pragma unroll
    for (int kk = 0; kk < 4; ++kk)
        za[kk] = *(const bf16x8*)&zrow[kk * 32 + kbase];

    f32x4 acc[8];
    #pragma unroll
    for (int ct = 0; ct < 8; ++ct) acc[ct] = (f32x4){0.f, 0.f, 0.f, 0.f};
    #pragma unroll
    for (int kk = 0; kk < 4; ++kk) {
        #pragma unroll
        for (int ct = 0; ct < 8; ++ct) {
            int o = (ct * 16 + (lane & 15)) * WPAD + kk * 32 + kbase;
            bf16x8 bh = *(const bf16x8*)&Wth[o];
            bf16x8 bl = *(const bf16x8*)&Wtl[o];
            acc[ct] = __builtin_amdgcn_mfma_f32_16x16x32_bf16(za[kk], bh, acc[ct], 0, 0, 0);
            acc[ct] = __builtin_amdgcn_mfma_f32_16x16x32_bf16(za[kk], bl, acc[ct], 0, 0, 0);
        }
    }

    float bbv = bb[0];
    int r0 = rowBase + w * 16 + ((lane >> 4) << 2);
    float pos[4] = {0.f, 0.f, 0.f, 0.f}, neg[4] = {0.f, 0.f, 0.f, 0.f};
    #pragma unroll
    for (int r = 0; r < 4; ++r) {
        int gr = (r0 + r < NN) ? r0 + r : NN - 1;
        int pr = perm[gr];
        const unsigned short* zr = &zbf[(size_t)gr * HD];
        const unsigned short* zp = &zbf[(size_t)pr * HD];
        #pragma unroll
        for (int ct = 0; ct < 8; ++ct) {
            float tv = acc[ct][r];
            int col = ct * 16 + (lane & 15);
            pos[r] += tv * b2f(zr[col]);
            neg[r] += tv * b2f(zp[col]);
        }
    }
    #pragma unroll
    for (int r = 0; r < 4; ++r) {
        #pragma unroll
        for (int off = 1; off < 16; off <<= 1) {
            pos[r] += __shfl_xor(pos[r], off);
            neg[r] += __shfl_xor(neg[r], off);
        }
    }
    if ((lane & 15) == 0) {
        #pragma unroll
        for (int r = 0; r < 4; ++r) {
            int gr = r0 + r;
            if (gr < NN) {
                out[gr] = pos[r] + bbv;
                out[NN + gr] = neg[r] + bbv;
            }
        }
    }
}

extern "C" void kernel_launch(void* const* d_in, const int* in_sizes, int n_in,
                              void* d_out, int out_size, void* d_ws, size_t ws_size,
                              hipStream_t stream) {
    const float* x    = (const float*)d_in[0];
    const float* W    = (const float*)d_in[1];
    const float* b    = (const float*)d_in[2];
    const float* Wb   = (const float*)d_in[3];
    const float* bb   = (const float*)d_in[4];
    const int*   ei   = (const int*)d_in[5];
    const int*   perm = (const int*)d_in[6];
    float* out = (float*)d_out;

    char* ws = (char*)d_ws;
    int*            cursor   = (int*)(ws + 0);               // 4 KB
    float*          dinv     = (float*)(ws + 0x1000);        // 200 KB
    int*            rowstart = (int*)(ws + 0x33000);         // 200 KB
    int*            degi     = (int*)(ws + 0x65000);         // 200 KB
    unsigned short* csr      = (unsigned short*)(ws + 0x97000);   // 1.6 MB
    unsigned*       binned   = (unsigned*)(ws + 0x240000);   // 3.6 MB
    unsigned short* Wtg      = (unsigned short*)(ws + 0x5B0000);  // 35 KB
    unsigned short* Wbth     = (unsigned short*)(ws + 0x5C0000);  // 35 KB
    unsigned short* Wbtl     = (unsigned short*)(ws + 0x5D0000);  // 35 KB
    unsigned short* ybf      = (unsigned short*)(ws + 0x600000);  // 12.8 MB
    unsigned short* zbf      = (unsigned short*)(ws + 0x2000000); // 12.8 MB

    k_prep<<<(HD * HD + 255) / 256, 256, 0, stream>>>(W, Wb, cursor, Wtg, Wbth, Wbtl);
    k_fused1<<<GEMM_BLOCKS + BIN_BLOCKS, 256, 0, stream>>>(x, Wtg, ybf, ei, cursor, binned);
    k_csr<<<NBINS, 256, 0, stream>>>(binned, cursor, csr, rowstart, degi, dinv);
    k_gather<<<(NN + 7) / 8, 256, 0, stream>>>(csr, rowstart, degi, dinv, ybf, b, zbf);
    k_bilinear<<<GEMM_BLOCKS, 256, 0, stream>>>(zbf, Wbth, Wbtl, bb, perm, out);
}

// Round 10
// 93.937 us; speedup vs baseline: 1.9313x; 1.0119x over previous
//
#include <hip/hip_runtime.h>
#include <hip/hip_bf16.h>

#define NN 50000
#define NE 800000
#define HD 128
#define WPAD 136                // transposed-W LDS/global row stride (shorts), 16B-aligned

#define BINSH 9                 // 512 nodes per coarse bin
#define NBINS 98                // ceil(50000/512)
#define BINCAP 9216             // slop capacity (mean 8163, 11.6 sigma)
#define CHUNK 1024              // edges per binplace block (782 blocks)
#define MAXBIN 9216

#define GEMM_BLOCKS ((NN + 63) / 64)          // 782
#define BIN_BLOCKS  ((NE + CHUNK - 1) / CHUNK) // 782

typedef __attribute__((ext_vector_type(8))) short bf16x8;
typedef __attribute__((ext_vector_type(4))) float f32x4;

// f32 -> bf16 round-to-nearest-even
__device__ inline unsigned short f2bf(float f) {
    union { float f; unsigned u; } c; c.f = f;
    unsigned r = c.u + 0x7fff + ((c.u >> 16) & 1);
    return (unsigned short)(r >> 16);
}

__device__ inline float bflo(unsigned u) { return __uint_as_float(u << 16); }
__device__ inline float bfhi(unsigned u) { return __uint_as_float(u & 0xffff0000u); }
__device__ inline float b2f(unsigned short u) { return __uint_as_float(((unsigned)u) << 16); }

// ---------------- prep: cursor init + W^T bf16 + Wb^T bf16 tables ----------------
__global__ __launch_bounds__(256) void k_prep(
        const float* __restrict__ W, const float* __restrict__ Wb, int* cursor,
        unsigned short* __restrict__ Wtg, unsigned short* __restrict__ Wbth) {
    int t = threadIdx.x;
    if (blockIdx.x == 0 && t < NBINS) cursor[t] = t * BINCAP;
    int idx = blockIdx.x * 256 + t;
    if (idx < HD * HD) {
        int h = idx >> 7, c = idx & 127;        // W[h][c]
        Wtg[c * WPAD + h] = f2bf(W[idx]);
        Wbth[c * WPAD + h] = f2bf(Wb[idx]);
    }
}

// ---------------- fused: blocks [0,782) MFMA GEMM, blocks [782,1564) edge binning ----------------
__global__ __launch_bounds__(256) void k_fused1(
        const float* __restrict__ x, const unsigned short* __restrict__ Wtg,
        unsigned short* __restrict__ ybf,
        const int* __restrict__ ei, int* cursor, unsigned* __restrict__ binned) {
    __shared__ union {
        unsigned short Wt[HD * WPAD];           // 34816 B
        struct {
            unsigned stage[CHUNK];
            unsigned char sbin[CHUNK];
            int hist[NBINS], base[NBINS], cur[NBINS], gbase[NBINS];
        } p;
    } sh;
    int t = threadIdx.x;

    if (blockIdx.x < GEMM_BLOCKS) {
        // ---- GEMM: ybf = bf16(x @ W)  (dinv applied later in gather) ----
        int rowBase = blockIdx.x * 64;
        const uint4* src = (const uint4*)Wtg;
        uint4* dst = (uint4*)sh.Wt;
        #pragma unroll
        for (int i = 0; i < 9; ++i) {
            int f = t + i * 256;
            if (f < (HD * WPAD * 2) / 16) dst[f] = src[f];
        }
        __syncthreads();

        int w = t >> 6, lane = t & 63;
        int row = rowBase + w * 16 + (lane & 15);
        int rowc = row < NN ? row : NN - 1;
        int kbase = (lane >> 4) * 8;

        bf16x8 ah[4];
        const float* xrow = &x[(size_t)rowc * HD];
        #pragma unroll
        for (int kk = 0; kk < 4; ++kk) {
            float4 u0 = *(const float4*)(xrow + kk * 32 + kbase);
            float4 u1 = *(const float4*)(xrow + kk * 32 + kbase + 4);
            ah[kk][0] = (short)f2bf(u0.x); ah[kk][1] = (short)f2bf(u0.y);
            ah[kk][2] = (short)f2bf(u0.z); ah[kk][3] = (short)f2bf(u0.w);
            ah[kk][4] = (short)f2bf(u1.x); ah[kk][5] = (short)f2bf(u1.y);
            ah[kk][6] = (short)f2bf(u1.z); ah[kk][7] = (short)f2bf(u1.w);
        }

        f32x4 acc[8];
        #pragma unroll
        for (int ct = 0; ct < 8; ++ct) acc[ct] = (f32x4){0.f, 0.f, 0.f, 0.f};
        #pragma unroll
        for (int kk = 0; kk < 4; ++kk) {
            #pragma unroll
            for (int ct = 0; ct < 8; ++ct) {
                bf16x8 bfr = *(const bf16x8*)&sh.Wt[(ct * 16 + (lane & 15)) * WPAD + kk * 32 + kbase];
                acc[ct] = __builtin_amdgcn_mfma_f32_16x16x32_bf16(ah[kk], bfr, acc[ct], 0, 0, 0);
            }
        }

        int r0 = rowBase + w * 16 + ((lane >> 4) << 2);
        #pragma unroll
        for (int r = 0; r < 4; ++r) {
            int gr = r0 + r;
            if (gr >= NN) continue;
            size_t basei = (size_t)gr * HD;
            #pragma unroll
            for (int ct = 0; ct < 8; ++ct)
                ybf[basei + ct * 16 + (lane & 15)] = f2bf(acc[ct][r]);
        }
    } else {
        // ---- binplace: bin edges by dst>>9, coalesced writes ----
        int e0 = (blockIdx.x - GEMM_BLOCKS) * CHUNK;
        int nE = NE - e0; if (nE > CHUNK) nE = CHUNK;

        if (t < NBINS) sh.p.hist[t] = 0;
        __syncthreads();

        unsigned keys[CHUNK / 256], packs[CHUNK / 256];
        #pragma unroll
        for (int i = 0; i < CHUNK / 256; ++i) {
            int li = i * 256 + t;
            keys[i] = 0xffffffffu;
            if (li < nE) {
                int e = e0 + li;
                unsigned s = (unsigned)ei[e];
                unsigned d = (unsigned)ei[NE + e];
                if (s < NN && d < NN) {
                    keys[i] = d >> BINSH;
                    packs[i] = (s << BINSH) | (d & ((1u << BINSH) - 1));
                    atomicAdd(&sh.p.hist[keys[i]], 1);
                }
            }
        }
        __syncthreads();
        if (t == 0) { int a = 0; for (int b = 0; b < NBINS; ++b) { sh.p.base[b] = a; a += sh.p.hist[b]; } }
        __syncthreads();
        if (t < NBINS) {
            sh.p.cur[t] = sh.p.base[t];
            if (sh.p.hist[t] > 0) sh.p.gbase[t] = atomicAdd(&cursor[t], sh.p.hist[t]);
        }
        __syncthreads();
        #pragma unroll
        for (int i = 0; i < CHUNK / 256; ++i) {
            if (keys[i] != 0xffffffffu) {
                int p = atomicAdd(&sh.p.cur[keys[i]], 1);
                sh.p.stage[p] = packs[i];
                sh.p.sbin[p] = (unsigned char)keys[i];
            }
        }
        __syncthreads();
        int tot = sh.p.cur[NBINS - 1];
        for (int j = t; j < tot; j += 256) {
            unsigned b = sh.p.sbin[j];
            binned[sh.p.gbase[b] + (j - sh.p.base[b])] = sh.p.stage[j];
        }
    }
}

// ---------------- pass 2: per-bin sort -> CSR (u16 src), deg/dinv/rowstart ----------------
__global__ __launch_bounds__(512) void k_csr(
        const unsigned* __restrict__ binned, const int* __restrict__ cursor,
        unsigned short* __restrict__ csr, int* __restrict__ rowstart,
        int* __restrict__ degi, float* __restrict__ dinv) {
    __shared__ unsigned ent[MAXBIN];
    __shared__ unsigned short outv[MAXBIN];
    __shared__ int hist[512], rs[512], cur[512];
    __shared__ int sizes[NBINS];
    int t = threadIdx.x, b = blockIdx.x;

    if (t < NBINS) sizes[t] = cursor[t] - t * BINCAP;
    __syncthreads();
    int bsize = sizes[b]; if (bsize > MAXBIN) bsize = MAXBIN;
    int bstart = 0;
    for (int i = 0; i < b; ++i) bstart += sizes[i];

    for (int j = t; j < bsize; j += 512) ent[j] = binned[b * BINCAP + j];
    if (t < 512) hist[t] = 0;
    __syncthreads();
    for (int j = t; j < bsize; j += 512) atomicAdd(&hist[ent[j] & 511], 1);
    __syncthreads();
    if (t == 0) { int a = 0; for (int k = 0; k < 512; ++k) { rs[k] = a; a += hist[k]; } }
    __syncthreads();
    if (t < 512) {
        cur[t] = rs[t];
        int g = (b << BINSH) + t;
        if (g < NN) {
            rowstart[g] = bstart + rs[t];
            degi[g] = hist[t];
            dinv[g] = rsqrtf((float)(hist[t] + 1));
        }
    }
    __syncthreads();
    for (int j = t; j < bsize; j += 512) {
        unsigned v = ent[j];
        int p = atomicAdd(&cur[v & 511], 1);
        outv[p] = (unsigned short)(v >> BINSH);
    }
    __syncthreads();
    for (int j = t; j < bsize; j += 512) csr[bstart + j] = outv[j];
}

// ---------------- gather: zbf[n] = bf16(dinv[n]*(y[n]*dinv[n] + sum y[s]*dinv[s]) + b) ----------------
// 16 lanes per node, 8 cols (16 B) per lane.
__global__ __launch_bounds__(256) void k_gather(
        const unsigned short* __restrict__ csr, const int* __restrict__ rowstart,
        const int* __restrict__ degi, const float* __restrict__ dinv,
        const unsigned short* __restrict__ ybf, const float* __restrict__ b,
        unsigned short* __restrict__ zbf) {
    int t = threadIdx.x;
    int n = blockIdx.x * 16 + (t >> 4);
    int lane = t & 15;
    if (n >= NN) return;
    int c = lane * 8;

    float dvn = dinv[n];
    float acc[8];
    {
        uint4 q = *(const uint4*)&ybf[(size_t)n * HD + c];
        acc[0] = bflo(q.x) * dvn; acc[1] = bfhi(q.x) * dvn;
        acc[2] = bflo(q.y) * dvn; acc[3] = bfhi(q.y) * dvn;
        acc[4] = bflo(q.z) * dvn; acc[5] = bfhi(q.z) * dvn;
        acc[6] = bflo(q.w) * dvn; acc[7] = bfhi(q.w) * dvn;
    }
    int beg = rowstart[n];
    int dg = degi[n];

    int i = 0;
    for (; i + 8 <= dg; i += 8) {
        int ss[8];
        #pragma unroll
        for (int u = 0; u < 8; ++u) ss[u] = csr[beg + i + u];
        float dd[8];
        uint4 q[8];
        #pragma unroll
        for (int u = 0; u < 8; ++u) {
            dd[u] = dinv[ss[u]];
            q[u] = *(const uint4*)&ybf[(size_t)ss[u] * HD + c];
        }
        #pragma unroll
        for (int u = 0; u < 8; ++u) {
            acc[0] += bflo(q[u].x) * dd[u]; acc[1] += bfhi(q[u].x) * dd[u];
            acc[2] += bflo(q[u].y) * dd[u]; acc[3] += bfhi(q[u].y) * dd[u];
            acc[4] += bflo(q[u].z) * dd[u]; acc[5] += bfhi(q[u].z) * dd[u];
            acc[6] += bflo(q[u].w) * dd[u]; acc[7] += bfhi(q[u].w) * dd[u];
        }
    }
    for (; i < dg; ++i) {
        int s = csr[beg + i];
        float ds = dinv[s];
        uint4 q = *(const uint4*)&ybf[(size_t)s * HD + c];
        acc[0] += bflo(q.x) * ds; acc[1] += bfhi(q.x) * ds;
        acc[2] += bflo(q.y) * ds; acc[3] += bfhi(q.y) * ds;
        acc[4] += bflo(q.z) * ds; acc[5] += bfhi(q.z) * ds;
        acc[6] += bflo(q.w) * ds; acc[7] += bfhi(q.w) * ds;
    }

    float4 bv0 = *(const float4*)&b[c];
    float4 bv1 = *(const float4*)&b[c + 4];
    unsigned o0 = (unsigned)f2bf(acc[0] * dvn + bv0.x) | ((unsigned)f2bf(acc[1] * dvn + bv0.y) << 16);
    unsigned o1 = (unsigned)f2bf(acc[2] * dvn + bv0.z) | ((unsigned)f2bf(acc[3] * dvn + bv0.w) << 16);
    unsigned o2 = (unsigned)f2bf(acc[4] * dvn + bv1.x) | ((unsigned)f2bf(acc[5] * dvn + bv1.y) << 16);
    unsigned o3 = (unsigned)f2bf(acc[6] * dvn + bv1.z) | ((unsigned)f2bf(acc[7] * dvn + bv1.w) << 16);
    uint4 o = make_uint4(o0, o1, o2, o3);
    *(uint4*)&zbf[(size_t)n * HD + c] = o;
}

// ---------------- MFMA bilinear: t = zbf@Wb (1-pass); pos=<t,z>, neg=<t,z[perm]> ----------------
__global__ __launch_bounds__(256) void k_bilinear(
        const unsigned short* __restrict__ zbf,
        const unsigned short* __restrict__ Wbth,
        const float* __restrict__ bb, const int* __restrict__ perm,
        float* __restrict__ out) {
    __shared__ unsigned short Wth[HD * WPAD];   // Wb^T bf16, 34.8 KB
    int t = threadIdx.x;
    int rowBase = blockIdx.x * 64;

    {
        const uint4* shp = (const uint4*)Wbth;
        uint4* dh = (uint4*)Wth;
        #pragma unroll
        for (int i = 0; i < 9; ++i) {
            int f = t + i * 256;
            if (f < (HD * WPAD * 2) / 16) dh[f] = shp[f];
        }
    }
    __syncthreads();

    int w = t >> 6, lane = t & 63;
    int row = rowBase + w * 16 + (lane & 15);
    int rowc = row < NN ? row : NN - 1;
    int kbase = (lane >> 4) * 8;

    bf16x8 za[4];
    const unsigned short* zrow = &zbf[(size_t)rowc * HD];
    #pragma unroll
    for (int kk = 0; kk < 4; ++kk)
        za[kk] = *(const bf16x8*)&zrow[kk * 32 + kbase];

    f32x4 acc[8];
    #pragma unroll
    for (int ct = 0; ct < 8; ++ct) acc[ct] = (f32x4){0.f, 0.f, 0.f, 0.f};
    #pragma unroll
    for (int kk = 0; kk < 4; ++kk) {
        #pragma unroll
        for (int ct = 0; ct < 8; ++ct) {
            bf16x8 bh = *(const bf16x8*)&Wth[(ct * 16 + (lane & 15)) * WPAD + kk * 32 + kbase];
            acc[ct] = __builtin_amdgcn_mfma_f32_16x16x32_bf16(za[kk], bh, acc[ct], 0, 0, 0);
        }
    }

    float bbv = bb[0];
    int r0 = rowBase + w * 16 + ((lane >> 4) << 2);
    float pos[4] = {0.f, 0.f, 0.f, 0.f}, neg[4] = {0.f, 0.f, 0.f, 0.f};
    #pragma unroll
    for (int r = 0; r < 4; ++r) {
        int gr = (r0 + r < NN) ? r0 + r : NN - 1;
        int pr = perm[gr];
        const unsigned short* zr = &zbf[(size_t)gr * HD];
        const unsigned short* zp = &zbf[(size_t)pr * HD];
        #pragma unroll
        for (int ct = 0; ct < 8; ++ct) {
            float tv = acc[ct][r];
            int col = ct * 16 + (lane & 15);
            pos[r] += tv * b2f(zr[col]);
            neg[r] += tv * b2f(zp[col]);
        }
    }
    #pragma unroll
    for (int r = 0; r < 4; ++r) {
        #pragma unroll
        for (int off = 1; off < 16; off <<= 1) {
            pos[r] += __shfl_xor(pos[r], off);
            neg[r] += __shfl_xor(neg[r], off);
        }
    }
    if ((lane & 15) == 0) {
        #pragma unroll
        for (int r = 0; r < 4; ++r) {
            int gr = r0 + r;
            if (gr < NN) {
                out[gr] = pos[r] + bbv;
                out[NN + gr] = neg[r] + bbv;
            }
        }
    }
}

extern "C" void kernel_launch(void* const* d_in, const int* in_sizes, int n_in,
                              void* d_out, int out_size, void* d_ws, size_t ws_size,
                              hipStream_t stream) {
    const float* x    = (const float*)d_in[0];
    const float* W    = (const float*)d_in[1];
    const float* b    = (const float*)d_in[2];
    const float* Wb   = (const float*)d_in[3];
    const float* bb   = (const float*)d_in[4];
    const int*   ei   = (const int*)d_in[5];
    const int*   perm = (const int*)d_in[6];
    float* out = (float*)d_out;

    char* ws = (char*)d_ws;
    int*            cursor   = (int*)(ws + 0);               // 4 KB
    float*          dinv     = (float*)(ws + 0x1000);        // 200 KB
    int*            rowstart = (int*)(ws + 0x33000);         // 200 KB
    int*            degi     = (int*)(ws + 0x65000);         // 200 KB
    unsigned short* csr      = (unsigned short*)(ws + 0x97000);   // 1.6 MB
    unsigned*       binned   = (unsigned*)(ws + 0x240000);   // 3.6 MB
    unsigned short* Wtg      = (unsigned short*)(ws + 0x5B0000);  // 35 KB
    unsigned short* Wbth     = (unsigned short*)(ws + 0x5C0000);  // 35 KB
    unsigned short* ybf      = (unsigned short*)(ws + 0x600000);  // 12.8 MB
    unsigned short* zbf      = (unsigned short*)(ws + 0x2000000); // 12.8 MB

    k_prep<<<(HD * HD + 255) / 256, 256, 0, stream>>>(W, Wb, cursor, Wtg, Wbth);
    k_fused1<<<GEMM_BLOCKS + BIN_BLOCKS, 256, 0, stream>>>(x, Wtg, ybf, ei, cursor, binned);
    k_csr<<<NBINS, 512, 0, stream>>>(binned, cursor, csr, rowstart, degi, dinv);
    k_gather<<<(NN + 15) / 16, 256, 0, stream>>>(csr, rowstart, degi, dinv, ybf, b, zbf);
    k_bilinear<<<GEMM_BLOCKS, 256, 0, stream>>>(zbf, Wbth, bb, perm, out);
}